// Round 6
// baseline (929.347 us; speedup 1.0000x reference)
//
#include <hip/hip_runtime.h>

#define D_CODES 2048
#define C_DIM   256
#define MOM     0.99f
#define ONE_M   0.01f
#define EPSI    1e-5f
#define TAU     0.15f
#define RCAP    16384
#define SBCAP   2304

// output offsets (floats)
#define Q_OFF    0
#define LOSS_OFF 16777216
#define IDS_OFF  16777217
#define NE_OFF   16842753
#define NCS_OFF  17367041
#define NEA_OFF  17369089

// workspace offsets (floats)
#define WS_ICNT    0
#define WS_CNTF    2048
#define WS_OFFS    4096
#define WS_CURS    6144
#define WS_SUMX2   10240
#define WS_NTOT    11264
#define WS_RCNT    11268
#define WS_NSB     11269
#define WS_NORMS   11272
#define WS_RLIST   13320
#define WS_ESUM    29704
#define WS_E2      553992
#define WS_KEYH    816136
#define WS_M2H     1078280
#define WS_PLIST   1209352
#define WS_SBCODE  1274888
#define WS_SBSTART 1277192
#define WS_SBINFO  1279496
#define WS_LOSSP   1281800

typedef _Float16 half8 __attribute__((ext_vector_type(8)));
typedef __attribute__((ext_vector_type(4))) float f32x4;
typedef unsigned long long u64;

__device__ __forceinline__ f32x4 MFH(half8 a, half8 b, f32x4 c) {
    return __builtin_amdgcn_mfma_f32_16x16x32_f16(a, b, c, 0, 0, 0);
}
__device__ __forceinline__ unsigned enc_f(float v) {
    unsigned u = __float_as_uint(v);
    return (u & 0x80000000u) ? ~u : (u | 0x80000000u);
}
__device__ __forceinline__ float dec_f(unsigned u) {
    return (u & 0x80000000u) ? __uint_as_float(u & 0x7FFFFFFFu)
                             : __uint_as_float(~u);
}

// grid 2048: esum zero everywhere; blocks 0-63 eprep+norms; 64-71 icnt; 72-80 lossp; 81 rcnt
__global__ __launch_bounds__(256) void k_init(
    const float* __restrict__ embed, float* __restrict__ e2f,
    float* __restrict__ norms, float* __restrict__ esum,
    int* __restrict__ icnt, float* __restrict__ lossp,
    unsigned* __restrict__ rcnt)
{
    const int b = blockIdx.x, t = threadIdx.x;
    esum[(size_t)b * 256 + t] = 0.f;
    if (b < 64) {
        __shared__ float nrm[32];
        if (t < 32) nrm[t] = 0.f;
        __syncthreads();
        char* e2 = (char*)e2f;
        const int s = b;
        #pragma unroll
        for (int it = 0; it < 4; ++it) {
            int u = it * 256 + t;
            int r = u >> 9, kc = (u >> 6) & 7, l = u & 63;
            int code = s * 32 + r * 16 + (l & 15);
            int ch0  = kc * 32 + ((l >> 4) << 3);
            const float* src = embed + (size_t)code * C_DIM + ch0;
            float4 v0 = *(const float4*)src;
            float4 v1 = *(const float4*)(src + 4);
            float vv[8] = {v0.x, v0.y, v0.z, v0.w, v1.x, v1.y, v1.z, v1.w};
            half8 hh;
            float p = 0.f;
            #pragma unroll
            for (int j = 0; j < 8; ++j) { hh[j] = (_Float16)vv[j]; p += vv[j] * vv[j]; }
            atomicAdd(&nrm[r * 16 + (l & 15)], p);
            char* dst = e2 + (size_t)s * 16384 + (size_t)((r * 8 + kc) * 64 + l) * 16;
            *(half8*)dst = hh;
        }
        __syncthreads();
        if (t < 32) norms[s * 32 + t] = nrm[t];
    } else if (b < 72) {
        icnt[(b - 64) * 256 + t] = 0;
    } else if (b < 81) {
        int j = (b - 72) * 256 + t;
        if (j < SBCAP) lossp[j] = 0.f;
    } else if (b == 81) {
        if (t == 0) *rcnt = 0u;
    }
}

__device__ __forceinline__ void stage_copy(const char* __restrict__ g, char* lds_base,
                                           int w, int l) {
    #pragma unroll
    for (int i = 0; i < 4; ++i) {
        int off = w * 4096 + i * 1024;
        __builtin_amdgcn_global_load_lds(
            (const __attribute__((address_space(1))) void*)(g + off + l * 16),
            (__attribute__((address_space(3))) void*)(lds_base + off),
            16, 0, 0);
    }
}

// grid 1024: blk = (bi*32+q)*2 + h; half h scans codes [h*1024, h*1024+1024)
// per-pixel top1/top2 written to keyh/m2h[h]; h0 writes sumx2 partials, h1 writes xt
__global__ __launch_bounds__(256, 4) void k_main(
    const float* __restrict__ x, const float* __restrict__ e2f,
    const float* __restrict__ norms, float* __restrict__ xt,
    float* __restrict__ sumx2p, u64* __restrict__ keyh,
    float* __restrict__ m2h)
{
    __shared__ char smem[34816];
    __shared__ float wred[4];
    const int t  = threadIdx.x;
    const int l  = t & 63;
    const int w  = __builtin_amdgcn_readfirstlane(t >> 6);
    const int blk = blockIdx.x;
    const int h  = blk & 1;
    const int q  = (blk >> 1) & 31;
    const int bi = blk >> 6;
    const char* e2 = (const char*)e2f + (size_t)h * 32 * 16384;

    half8 bxh[2][8], bxl[2][8];
    float sx2 = 0.f;
    {
        float* xs = (float*)smem;     // [pl 128][68]
        const int hiq = w >> 1;
        const int wib = (w & 1) * 32;
        for (int c = 0; c < 4; ++c) {
            __syncthreads();
            #pragma unroll
            for (int k = 0; k < 8; ++k) {
                int u = k * 256 + t;
                int wi0 = (u & 15) * 4;
                int hq  = (u >> 4) & 1;
                int chl = u >> 5;
                float4 v = *(const float4*)(x + ((size_t)(bi * C_DIM + c * 64 + chl)) * 4096
                                              + (2 * q + hq) * 64 + wi0);
                if (h == 0) sx2 += v.x * v.x + v.y * v.y + v.z * v.z + v.w * v.w;
                int pb = (hq * 64 + wi0) * 68 + chl;
                xs[pb] = v.x; xs[pb + 68] = v.y; xs[pb + 136] = v.z; xs[pb + 204] = v.w;
            }
            __syncthreads();
            if (h == 1) {       // xt write (transposed, coalesced 256B chunks)
                int plo = t >> 4;
                int cc4 = (t & 15) * 4;
                #pragma unroll
                for (int p8 = 0; p8 < 8; ++p8) {
                    int pl = p8 * 16 + plo;
                    float4 f = *(const float4*)&xs[pl * 68 + cc4];
                    int hq = pl >> 6, wi = pl & 63;
                    size_t n = (size_t)bi * 4096 + (size_t)wi * 64 + (2 * q + hq);
                    *(float4*)(xt + n * C_DIM + c * 64 + cc4) = f;
                }
            }
            // x B-fragments: fp16 hi + fp16 residual
            #pragma unroll
            for (int kcl = 0; kcl < 2; ++kcl) {
                #pragma unroll
                for (int nt = 0; nt < 2; ++nt) {
                    int pl = hiq * 64 + wib + nt * 16 + (l & 15);
                    const float* src = &xs[pl * 68 + kcl * 32 + ((l >> 4) << 3)];
                    float4 f0 = *(const float4*)src;
                    float4 f1 = *(const float4*)(src + 4);
                    float vv[8] = {f0.x, f0.y, f0.z, f0.w, f1.x, f1.y, f1.z, f1.w};
                    half8 hh, rr;
                    #pragma unroll
                    for (int j = 0; j < 8; ++j) {
                        _Float16 hv = (_Float16)vv[j];
                        hh[j] = hv;
                        rr[j] = (_Float16)(vv[j] - (float)hv);
                    }
                    bxh[nt][c * 2 + kcl] = hh;
                    bxl[nt][c * 2 + kcl] = rr;
                }
            }
        }
        __syncthreads();
    }
    if (h == 0) {
        #pragma unroll
        for (int o = 32; o; o >>= 1) sx2 += __shfl_down(sx2, o);
        if (l == 0) wred[w] = sx2;
    }

    float m1[2] = {-3.4e38f, -3.4e38f}, m2[2] = {-3.4e38f, -3.4e38f};
    int   i1[2] = {0, 0};

    stage_copy(e2, smem, w, l);
    __syncthreads();

    for (int s = 0; s < 32; ++s) {
        char* cur = smem + (s & 1) * 16384;
        if (s < 31)
            stage_copy(e2 + (size_t)(s + 1) * 16384, smem + ((s + 1) & 1) * 16384, w, l);

        #pragma unroll
        for (int r = 0; r < 2; ++r) {
            f32x4 z = {0.f, 0.f, 0.f, 0.f};
            f32x4 aA0 = z, aL0 = z, aA1 = z, aL1 = z;
            #pragma unroll
            for (int kc = 0; kc < 8; ++kc) {
                half8 ah = *(const half8*)(cur + ((r * 8 + kc) * 64 + l) * 16);
                aA0 = MFH(ah, bxh[0][kc], aA0);
                aL0 = MFH(ah, bxl[0][kc], aL0);
                aA1 = MFH(ah, bxh[1][kc], aA1);
                aL1 = MFH(ah, bxl[1][kc], aL1);
            }
            int c0 = h * 1024 + s * 32 + r * 16 + ((l >> 4) << 2);
            float4 nrm = *(const float4*)(norms + c0);
            float nr[4] = {nrm.x, nrm.y, nrm.z, nrm.w};
            #pragma unroll
            for (int reg = 0; reg < 4; ++reg) {
                float s0 = 2.f * (aA0[reg] + aL0[reg]) - nr[reg];
                float s1 = 2.f * (aA1[reg] + aL1[reg]) - nr[reg];
                int code = c0 + reg;
                if (s0 > m1[0]) { m2[0] = m1[0]; m1[0] = s0; i1[0] = code; }
                else            { m2[0] = fmaxf(m2[0], s0); }
                if (s1 > m1[1]) { m2[1] = m1[1]; m1[1] = s1; i1[1] = code; }
                else            { m2[1] = fmaxf(m2[1], s1); }
            }
        }
        __syncthreads();
    }

    #pragma unroll
    for (int nt = 0; nt < 2; ++nt) {
        float a1 = m1[nt], a2 = m2[nt];
        int   ai = i1[nt];
        #pragma unroll
        for (int off = 16; off <= 32; off <<= 1) {
            float o1 = __shfl_xor(a1, off);
            int   oi = __shfl_xor(ai, off);
            float o2 = __shfl_xor(a2, off);
            if (o1 > a1)       { a2 = fmaxf(a1, o2); a1 = o1; ai = oi; }
            else if (o1 == a1) { if (oi < ai) ai = oi; a2 = a1; }
            else               { a2 = fmaxf(a2, o1); }
        }
        if (l < 16) {
            int wi = (w & 1) * 32 + nt * 16 + l;
            int hi_ = 2 * q + (w >> 1);
            int n = (bi << 12) + (wi << 6) + hi_;
            keyh[((size_t)h << 16) + n] = ((u64)enc_f(a1) << 32) | (unsigned)(~ai);
            m2h[(h << 16) + n] = a2;
        }
    }
    if (h == 0) {
        __syncthreads();
        if (t == 0) sumx2p[bi * 32 + q] = wred[0] + wred[1] + wred[2] + wred[3];
    }
}

// grid 256: merge halves -> ids + histogram + near-tie flags
__global__ __launch_bounds__(256) void k_merge(
    const u64* __restrict__ keyh, const float* __restrict__ m2h,
    float* __restrict__ out, int* __restrict__ icnt,
    unsigned* __restrict__ rcnt, int* __restrict__ rlist)
{
    int n = blockIdx.x * 256 + threadIdx.x;
    u64 kA = keyh[n], kB = keyh[65536 + n];
    float m2A = m2h[n], m2B = m2h[65536 + n];
    bool wA = kA >= kB;
    u64 kW = wA ? kA : kB, kL = wA ? kB : kA;
    float m2w = wA ? m2A : m2B;
    float sW = dec_f((unsigned)(kW >> 32));
    float sL = dec_f((unsigned)(kL >> 32));
    int code = (int)(~(unsigned)kW);
    out[IDS_OFF + n] = (float)code;
    atomicAdd(&icnt[code], 1);
    float gap = sW - fmaxf(m2w, sL);
    if (gap < TAU) {
        unsigned j = atomicAdd(rcnt, 1u);
        if (j < RCAP) rlist[j] = n;
    }
}

// grid 128: exact fp32 rescore of flagged pixels; writes final ids + icnt fixup
__global__ __launch_bounds__(256) void k_rescue(
    const float* __restrict__ x, const float* __restrict__ embed,
    const float* __restrict__ norms, const unsigned* __restrict__ rcnt,
    const int* __restrict__ rlist, float* __restrict__ out,
    int* __restrict__ icnt)
{
    __shared__ float xs[16][260];
    __shared__ int nn[16];
    __shared__ u64 rk[4][16];
    const int t = threadIdx.x;
    const int l = t & 63;
    const int w = t >> 6;
    int nf = (int)min(*rcnt, (unsigned)RCAP);
    int nch = (nf + 15) >> 4;
    for (int chunk = blockIdx.x; chunk < nch; chunk += gridDim.x) {
        __syncthreads();
        if (t < 16) nn[t] = rlist[(chunk * 16 + t < nf) ? (chunk * 16 + t) : chunk * 16];
        __syncthreads();
        #pragma unroll 4
        for (int p = 0; p < 16; ++p) {
            int n = nn[p];
            int bi = n >> 12, wi = (n >> 6) & 63, hi = n & 63;
            xs[p][t] = x[((size_t)(bi * C_DIM + t)) * 4096 + hi * 64 + wi];
        }
        __syncthreads();
        u64 bk[16];
        #pragma unroll
        for (int p = 0; p < 16; ++p) bk[p] = 0ull;
        for (int rep = 0; rep < 8; ++rep) {
            int d = rep * 256 + t;
            const float* er = embed + (size_t)d * C_DIM;
            float acc[16];
            #pragma unroll
            for (int p = 0; p < 16; ++p) acc[p] = 0.f;
            for (int c = 0; c < C_DIM; c += 4) {
                float4 e4 = *(const float4*)(er + c);
                #pragma unroll
                for (int p = 0; p < 16; ++p) {
                    float4 xv = *(const float4*)&xs[p][c];
                    acc[p] += xv.x * e4.x + xv.y * e4.y + xv.z * e4.z + xv.w * e4.w;
                }
            }
            float nrm = norms[d];
            #pragma unroll
            for (int p = 0; p < 16; ++p) {
                float sc = 2.f * acc[p] - nrm;
                u64 key = ((u64)enc_f(sc) << 32) | (unsigned)(~d);
                if (key > bk[p]) bk[p] = key;
            }
        }
        #pragma unroll
        for (int p = 0; p < 16; ++p) {
            u64 k0 = bk[p];
            #pragma unroll
            for (int o = 32; o; o >>= 1) {
                u64 ok = __shfl_down(k0, o);
                if (ok > k0) k0 = ok;
            }
            if (l == 0) rk[w][p] = k0;
        }
        __syncthreads();
        if (t < 16 && chunk * 16 + t < nf) {
            u64 k0 = rk[0][t];
            if (rk[1][t] > k0) k0 = rk[1][t];
            if (rk[2][t] > k0) k0 = rk[2][t];
            if (rk[3][t] > k0) k0 = rk[3][t];
            int n = nn[t];
            int newid = (int)(~(unsigned)k0);
            int old = (int)out[IDS_OFF + n];
            if (newid != old) {
                out[IDS_OFF + n] = (float)newid;
                atomicAdd(&icnt[old], -1);
                atomicAdd(&icnt[newid], 1);
            }
        }
    }
}

// single block: offsets + sub-block table + cntf + ntot
__global__ __launch_bounds__(256) void k_prefix(const int* __restrict__ icnt,
                                                const float* __restrict__ cs_in,
                                                int* __restrict__ offs,
                                                int* __restrict__ curs,
                                                float* __restrict__ cntf,
                                                int* __restrict__ sbcode,
                                                int* __restrict__ sbstart,
                                                int* __restrict__ sbinfo,
                                                int* __restrict__ nsbtot,
                                                float* __restrict__ ntot) {
    __shared__ int ps[256];
    __shared__ float fs[256];
    const int t = threadIdx.x;
    int c[8], o8[8];
    int s = 0;
    #pragma unroll
    for (int j = 0; j < 8; ++j) c[j] = icnt[t * 8 + j];
    #pragma unroll
    for (int j = 0; j < 8; ++j) { int tmp = c[j]; c[j] = s; s += tmp; }
    ps[t] = s;
    __syncthreads();
    for (int off = 1; off < 256; off <<= 1) {
        int v = (t >= off) ? ps[t - off] : 0;
        __syncthreads();
        ps[t] += v;
        __syncthreads();
    }
    int base = ps[t] - s;
    #pragma unroll
    for (int j = 0; j < 8; ++j) {
        int o = base + c[j];
        o8[j] = o;
        offs[t * 8 + j] = o;
        curs[t * 8 + j] = o;
        cntf[t * 8 + j] = (float)(icnt[t * 8 + j]);
    }
    int s2 = 0;
    int nb[8];
    #pragma unroll
    for (int j = 0; j < 8; ++j) {
        int cnt = icnt[t * 8 + j];
        nb[j] = (cnt + 255) >> 8;
        s2 += nb[j];
    }
    __syncthreads();
    ps[t] = s2;
    __syncthreads();
    for (int off = 1; off < 256; off <<= 1) {
        int v = (t >= off) ? ps[t - off] : 0;
        __syncthreads();
        ps[t] += v;
        __syncthreads();
    }
    int pos = ps[t] - s2;
    #pragma unroll
    for (int j = 0; j < 8; ++j) {
        int code = t * 8 + j;
        int cnt = icnt[code];
        int n = nb[j];
        for (int k = 0; k < n; ++k) {
            sbcode[pos]  = code;
            sbstart[pos] = o8[j] + k * 256;
            int len = cnt - k * 256; if (len > 256) len = 256;
            sbinfo[pos]  = len | ((n > 1) ? (1 << 16) : 0);
            ++pos;
        }
    }
    if (t == 255) *nsbtot = ps[255];
    // ntot = 0.99 * sum(cs_in) + 0.01 * 65536 (assignment-independent)
    float s3 = 0.f;
    #pragma unroll
    for (int j = 0; j < 8; ++j) s3 += cs_in[t * 8 + j];
    fs[t] = s3;
    __syncthreads();
    for (int o = 128; o; o >>= 1) { if (t < o) fs[t] += fs[t + o]; __syncthreads(); }
    if (t == 0) *ntot = MOM * fs[0] + ONE_M * 65536.0f;
}

__global__ __launch_bounds__(256) void k_scatter(const float* __restrict__ out,
                                                 int* __restrict__ curs,
                                                 int* __restrict__ plist) {
    int n = blockIdx.x * 256 + threadIdx.x;
    int id = (int)out[IDS_OFF + n];
    int pos = atomicAdd(&curs[id], 1);
    plist[pos] = n;
}

// grid-stride over sub-blocks: dense esum partials + per-sub-block loss term
__global__ __launch_bounds__(256) void k_esum(
    const float* __restrict__ xt, const float* __restrict__ embed,
    const float* __restrict__ norms, const int* __restrict__ sbcode,
    const int* __restrict__ sbstart, const int* __restrict__ sbinfo,
    const int* __restrict__ plist, const int* __restrict__ nsbtot,
    float* __restrict__ esum, float* __restrict__ lossp)
{
    __shared__ int   ns[256];
    __shared__ float red[256];
    const int t = threadIdx.x;
    const int total = *nsbtot;
    for (int sb = blockIdx.x; sb < total; sb += gridDim.x) {
        const int d     = sbcode[sb];
        const int start = sbstart[sb];
        const int info  = sbinfo[sb];
        const int len   = info & 0xFFFF;
        const bool multi = (info >> 16) != 0;
        __syncthreads();
        if (t < len) ns[t] = plist[start + t];
        __syncthreads();
        float acc = 0.f;
        #pragma unroll 8
        for (int i = 0; i < len; ++i)
            acc += xt[(size_t)ns[i] * C_DIM + t];
        if (multi) atomicAdd(&esum[(size_t)t * D_CODES + d], acc);
        else       esum[(size_t)t * D_CODES + d] = acc;
        red[t] = acc * embed[(size_t)d * C_DIM + t];
        __syncthreads();
        for (int o = 128; o; o >>= 1) {
            if (t < o) red[t] += red[t + o];
            __syncthreads();
        }
        if (t == 0) lossp[sb] = 2.f * red[0] - (float)len * norms[d];
    }
}

// quantized output via LDS-staged embed rows (overwrites the xt region)
__global__ __launch_bounds__(256) void k_quant(
    const float* __restrict__ embed, float* __restrict__ out)
{
    __shared__ int   ids_s[64];
    __shared__ float es[32][257];
    const int t  = threadIdx.x;
    const int bi = blockIdx.x >> 6;
    const int hi = blockIdx.x & 63;
    const int wl = t & 31;
    const int cg = t >> 5;
    if (t < 64) ids_s[t] = (int)out[IDS_OFF + ((size_t)bi << 12) + (t << 6) + hi];
    __syncthreads();
    #pragma unroll
    for (int pass = 0; pass < 2; ++pass) {
        #pragma unroll 8
        for (int p = 0; p < 32; ++p) {
            es[p][t] = embed[(size_t)ids_s[pass * 32 + p] * C_DIM + t];
        }
        __syncthreads();
        #pragma unroll 8
        for (int k = 0; k < 32; ++k) {
            int ch = k * 8 + cg;
            out[Q_OFF + ((size_t)(bi * C_DIM + ch)) * 4096 + hi * 64 + pass * 32 + wl]
                = es[wl][ch];
        }
        __syncthreads();
    }
}

// grid 2049: blocks 0-2047 embed-EMA+new_embed (+NCS via blocks 0-7); block 2048 loss
__global__ __launch_bounds__(256) void k_final(
    const float* __restrict__ cs_in, const float* __restrict__ cntf,
    const float* __restrict__ embed_avg, const float* __restrict__ esum,
    const float* __restrict__ ntotp, const float* __restrict__ lossp,
    const float* __restrict__ sumx2p, float* __restrict__ out)
{
    const int b = blockIdx.x;
    const int t = threadIdx.x;
    if (b < 2048) {
        int ch = b >> 3;
        int d  = ((b & 7) << 8) + t;
        float ntot = *ntotp;
        float ncs  = MOM * cs_in[d] + ONE_M * cntf[d];
        if (b < 8) out[NCS_OFF + d] = ncs;
        float csm  = ntot * (ncs + EPSI) / (ntot + (float)D_CODES * EPSI);
        size_t i = (size_t)ch * D_CODES + d;
        float nea = MOM * embed_avg[i] + ONE_M * esum[i];
        out[NEA_OFF + i] = nea;
        out[NE_OFF + (size_t)d * C_DIM + ch] = nea / csm;
    } else {
        __shared__ float sm[256];
        float s1 = 0.f;
        for (int i = t; i < 512; i += 256) s1 += sumx2p[i];
        float s2 = 0.f;
        for (int i = t; i < SBCAP; i += 256) s2 += lossp[i];
        sm[t] = s1 - s2;
        __syncthreads();
        for (int o = 128; o; o >>= 1) { if (t < o) sm[t] += sm[t + o]; __syncthreads(); }
        if (t == 0) out[LOSS_OFF] = sm[0] / 16777216.f;
    }
}

extern "C" void kernel_launch(void* const* d_in, const int* in_sizes, int n_in,
                              void* d_out, int out_size, void* d_ws, size_t ws_size,
                              hipStream_t stream) {
    const float* x     = (const float*)d_in[0];
    const float* embed = (const float*)d_in[1];
    const float* cs    = (const float*)d_in[2];
    const float* ea    = (const float*)d_in[3];
    float* out = (float*)d_out;
    float* ws  = (float*)d_ws;
    int*      icnt    = (int*)(ws + WS_ICNT);
    float*    cntf    = ws + WS_CNTF;
    int*      offs    = (int*)(ws + WS_OFFS);
    int*      curs    = (int*)(ws + WS_CURS);
    float*    sumx2p  = ws + WS_SUMX2;
    float*    ntot    = ws + WS_NTOT;
    unsigned* rcnt    = (unsigned*)(ws + WS_RCNT);
    int*      nsbtot  = (int*)(ws + WS_NSB);
    float*    norms   = ws + WS_NORMS;
    int*      rlist   = (int*)(ws + WS_RLIST);
    float*    esum    = ws + WS_ESUM;
    float*    e2      = ws + WS_E2;
    u64*      keyh    = (u64*)(ws + WS_KEYH);
    float*    m2h     = ws + WS_M2H;
    int*      plist   = (int*)(ws + WS_PLIST);
    int*      sbcode  = (int*)(ws + WS_SBCODE);
    int*      sbstart = (int*)(ws + WS_SBSTART);
    int*      sbinfo  = (int*)(ws + WS_SBINFO);
    float*    lossp   = ws + WS_LOSSP;
    float*    xt      = out + Q_OFF;   // staged in quantized region, overwritten by k_quant

    k_init<<<2048, 256, 0, stream>>>(embed, e2, norms, esum, icnt, lossp, rcnt);
    k_main<<<1024, 256, 0, stream>>>(x, e2, norms, xt, sumx2p, keyh, m2h);
    k_merge<<<256, 256, 0, stream>>>(keyh, m2h, out, icnt, rcnt, rlist);
    k_rescue<<<128, 256, 0, stream>>>(x, embed, norms, rcnt, rlist, out, icnt);
    k_prefix<<<1, 256, 0, stream>>>(icnt, cs, offs, curs, cntf, sbcode, sbstart,
                                    sbinfo, nsbtot, ntot);
    k_scatter<<<256, 256, 0, stream>>>(out, curs, plist);
    k_esum<<<SBCAP, 256, 0, stream>>>(xt, embed, norms, sbcode, sbstart, sbinfo,
                                      plist, nsbtot, esum, lossp);
    k_quant<<<1024, 256, 0, stream>>>(embed, out);
    k_final<<<2049, 256, 0, stream>>>(cs, cntf, ea, esum, ntot, lossp, sumx2p, out);
}

// Round 7
// 516.222 us; speedup vs baseline: 1.8003x; 1.8003x over previous
//
#include <hip/hip_runtime.h>

#define D_CODES 2048
#define C_DIM   256
#define MOM     0.99f
#define ONE_M   0.01f
#define EPSI    1e-5f
#define TAU     0.15f
#define RCAP    16384
#define SBCAP   2304

// output offsets (floats)
#define Q_OFF    0
#define LOSS_OFF 16777216
#define IDS_OFF  16777217
#define NE_OFF   16842753
#define NCS_OFF  17367041
#define NEA_OFF  17369089

// workspace offsets (floats)
#define WS_ICNT    0
#define WS_CNTF    2048
#define WS_OFFS    4096
#define WS_CURS    6144
#define WS_SUMX2   10240
#define WS_NTOT    11264
#define WS_RCNT    11268
#define WS_NSB     11269
#define WS_NORMS   11272
#define WS_RLIST   13320
#define WS_ESUM    29704
#define WS_E2      553992
#define WS_KEYH    816136
#define WS_M2H     1078280
#define WS_PLIST   1209352
#define WS_SBCODE  1274888
#define WS_SBSTART 1277192
#define WS_SBINFO  1279496
#define WS_LOSSP   1281800

typedef _Float16 half8 __attribute__((ext_vector_type(8)));
typedef __attribute__((ext_vector_type(4))) float f32x4;
typedef unsigned long long u64;

__device__ __forceinline__ f32x4 MFH(half8 a, half8 b, f32x4 c) {
    return __builtin_amdgcn_mfma_f32_16x16x32_f16(a, b, c, 0, 0, 0);
}
__device__ __forceinline__ unsigned enc_f(float v) {
    unsigned u = __float_as_uint(v);
    return (u & 0x80000000u) ? ~u : (u | 0x80000000u);
}
__device__ __forceinline__ float dec_f(unsigned u) {
    return (u & 0x80000000u) ? __uint_as_float(u & 0x7FFFFFFFu)
                             : __uint_as_float(~u);
}

// grid 2048: esum zero everywhere; blocks 0-63 eprep+norms; 64-71 icnt; 72-80 lossp; 81 rcnt
__global__ __launch_bounds__(256) void k_init(
    const float* __restrict__ embed, float* __restrict__ e2f,
    float* __restrict__ norms, float* __restrict__ esum,
    int* __restrict__ icnt, float* __restrict__ lossp,
    unsigned* __restrict__ rcnt)
{
    const int b = blockIdx.x, t = threadIdx.x;
    esum[(size_t)b * 256 + t] = 0.f;
    if (b < 64) {
        __shared__ float nrm[32];
        if (t < 32) nrm[t] = 0.f;
        __syncthreads();
        char* e2 = (char*)e2f;
        const int s = b;
        #pragma unroll
        for (int it = 0; it < 4; ++it) {
            int u = it * 256 + t;
            int r = u >> 9, kc = (u >> 6) & 7, l = u & 63;
            int code = s * 32 + r * 16 + (l & 15);
            int ch0  = kc * 32 + ((l >> 4) << 3);
            const float* src = embed + (size_t)code * C_DIM + ch0;
            float4 v0 = *(const float4*)src;
            float4 v1 = *(const float4*)(src + 4);
            float vv[8] = {v0.x, v0.y, v0.z, v0.w, v1.x, v1.y, v1.z, v1.w};
            half8 hh;
            float p = 0.f;
            #pragma unroll
            for (int j = 0; j < 8; ++j) { hh[j] = (_Float16)vv[j]; p += vv[j] * vv[j]; }
            atomicAdd(&nrm[r * 16 + (l & 15)], p);
            char* dst = e2 + (size_t)s * 16384 + (size_t)((r * 8 + kc) * 64 + l) * 16;
            *(half8*)dst = hh;
        }
        __syncthreads();
        if (t < 32) norms[s * 32 + t] = nrm[t];
    } else if (b < 72) {
        icnt[(b - 64) * 256 + t] = 0;
    } else if (b < 81) {
        int j = (b - 72) * 256 + t;
        if (j < SBCAP) lossp[j] = 0.f;
    } else if (b == 81) {
        if (t == 0) *rcnt = 0u;
    }
}

__device__ __forceinline__ void stage_copy(const char* __restrict__ g, char* lds_base,
                                           int w, int l) {
    #pragma unroll
    for (int i = 0; i < 4; ++i) {
        int off = w * 4096 + i * 1024;
        __builtin_amdgcn_global_load_lds(
            (const __attribute__((address_space(1))) void*)(g + off + l * 16),
            (__attribute__((address_space(3))) void*)(lds_base + off),
            16, 0, 0);
    }
}

// grid 1024: blk = (bi*32+q)*2 + h; half h scans codes [h*1024, h*1024+1024)
// per-pixel top1/top2 written to keyh/m2h[h]; h0 writes sumx2 partials, h1 writes xt
// NOTE launch_bounds (256,2): (256,4) forced a 64-VGPR cap -> fragment spill ->
// 1.6 GB scratch traffic per dispatch (round-6 regression). VGPR=128 + LDS 35KB
// still allow 4 blocks/CU at runtime; the grid of 1024 provides them.
__global__ __launch_bounds__(256, 2) void k_main(
    const float* __restrict__ x, const float* __restrict__ e2f,
    const float* __restrict__ norms, float* __restrict__ xt,
    float* __restrict__ sumx2p, u64* __restrict__ keyh,
    float* __restrict__ m2h)
{
    __shared__ char smem[34816];
    __shared__ float wred[4];
    const int t  = threadIdx.x;
    const int l  = t & 63;
    const int w  = __builtin_amdgcn_readfirstlane(t >> 6);
    const int blk = blockIdx.x;
    const int h  = blk & 1;
    const int q  = (blk >> 1) & 31;
    const int bi = blk >> 6;
    const char* e2 = (const char*)e2f + (size_t)h * 32 * 16384;

    half8 bxh[2][8], bxl[2][8];
    float sx2 = 0.f;
    {
        float* xs = (float*)smem;     // [pl 128][68]
        const int hiq = w >> 1;
        const int wib = (w & 1) * 32;
        for (int c = 0; c < 4; ++c) {
            __syncthreads();
            #pragma unroll
            for (int k = 0; k < 8; ++k) {
                int u = k * 256 + t;
                int wi0 = (u & 15) * 4;
                int hq  = (u >> 4) & 1;
                int chl = u >> 5;
                float4 v = *(const float4*)(x + ((size_t)(bi * C_DIM + c * 64 + chl)) * 4096
                                              + (2 * q + hq) * 64 + wi0);
                if (h == 0) sx2 += v.x * v.x + v.y * v.y + v.z * v.z + v.w * v.w;
                int pb = (hq * 64 + wi0) * 68 + chl;
                xs[pb] = v.x; xs[pb + 68] = v.y; xs[pb + 136] = v.z; xs[pb + 204] = v.w;
            }
            __syncthreads();
            if (h == 1) {       // xt write (transposed, coalesced 256B chunks)
                int plo = t >> 4;
                int cc4 = (t & 15) * 4;
                #pragma unroll
                for (int p8 = 0; p8 < 8; ++p8) {
                    int pl = p8 * 16 + plo;
                    float4 f = *(const float4*)&xs[pl * 68 + cc4];
                    int hq = pl >> 6, wi = pl & 63;
                    size_t n = (size_t)bi * 4096 + (size_t)wi * 64 + (2 * q + hq);
                    *(float4*)(xt + n * C_DIM + c * 64 + cc4) = f;
                }
            }
            // x B-fragments: fp16 hi + fp16 residual
            #pragma unroll
            for (int kcl = 0; kcl < 2; ++kcl) {
                #pragma unroll
                for (int nt = 0; nt < 2; ++nt) {
                    int pl = hiq * 64 + wib + nt * 16 + (l & 15);
                    const float* src = &xs[pl * 68 + kcl * 32 + ((l >> 4) << 3)];
                    float4 f0 = *(const float4*)src;
                    float4 f1 = *(const float4*)(src + 4);
                    float vv[8] = {f0.x, f0.y, f0.z, f0.w, f1.x, f1.y, f1.z, f1.w};
                    half8 hh, rr;
                    #pragma unroll
                    for (int j = 0; j < 8; ++j) {
                        _Float16 hv = (_Float16)vv[j];
                        hh[j] = hv;
                        rr[j] = (_Float16)(vv[j] - (float)hv);
                    }
                    bxh[nt][c * 2 + kcl] = hh;
                    bxl[nt][c * 2 + kcl] = rr;
                }
            }
        }
        __syncthreads();
    }
    if (h == 0) {
        #pragma unroll
        for (int o = 32; o; o >>= 1) sx2 += __shfl_down(sx2, o);
        if (l == 0) wred[w] = sx2;
    }

    float m1[2] = {-3.4e38f, -3.4e38f}, m2[2] = {-3.4e38f, -3.4e38f};
    int   i1[2] = {0, 0};

    stage_copy(e2, smem, w, l);
    __syncthreads();

    for (int s = 0; s < 32; ++s) {
        char* cur = smem + (s & 1) * 16384;
        if (s < 31)
            stage_copy(e2 + (size_t)(s + 1) * 16384, smem + ((s + 1) & 1) * 16384, w, l);

        #pragma unroll
        for (int r = 0; r < 2; ++r) {
            f32x4 z = {0.f, 0.f, 0.f, 0.f};
            f32x4 aA0 = z, aL0 = z, aA1 = z, aL1 = z;
            #pragma unroll
            for (int kc = 0; kc < 8; ++kc) {
                half8 ah = *(const half8*)(cur + ((r * 8 + kc) * 64 + l) * 16);
                aA0 = MFH(ah, bxh[0][kc], aA0);
                aL0 = MFH(ah, bxl[0][kc], aL0);
                aA1 = MFH(ah, bxh[1][kc], aA1);
                aL1 = MFH(ah, bxl[1][kc], aL1);
            }
            int c0 = h * 1024 + s * 32 + r * 16 + ((l >> 4) << 2);
            float4 nrm = *(const float4*)(norms + c0);
            float nr[4] = {nrm.x, nrm.y, nrm.z, nrm.w};
            #pragma unroll
            for (int reg = 0; reg < 4; ++reg) {
                float s0 = 2.f * (aA0[reg] + aL0[reg]) - nr[reg];
                float s1 = 2.f * (aA1[reg] + aL1[reg]) - nr[reg];
                int code = c0 + reg;
                if (s0 > m1[0]) { m2[0] = m1[0]; m1[0] = s0; i1[0] = code; }
                else            { m2[0] = fmaxf(m2[0], s0); }
                if (s1 > m1[1]) { m2[1] = m1[1]; m1[1] = s1; i1[1] = code; }
                else            { m2[1] = fmaxf(m2[1], s1); }
            }
        }
        __syncthreads();
    }

    #pragma unroll
    for (int nt = 0; nt < 2; ++nt) {
        float a1 = m1[nt], a2 = m2[nt];
        int   ai = i1[nt];
        #pragma unroll
        for (int off = 16; off <= 32; off <<= 1) {
            float o1 = __shfl_xor(a1, off);
            int   oi = __shfl_xor(ai, off);
            float o2 = __shfl_xor(a2, off);
            if (o1 > a1)       { a2 = fmaxf(a1, o2); a1 = o1; ai = oi; }
            else if (o1 == a1) { if (oi < ai) ai = oi; a2 = a1; }
            else               { a2 = fmaxf(a2, o1); }
        }
        if (l < 16) {
            int wi = (w & 1) * 32 + nt * 16 + l;
            int hi_ = 2 * q + (w >> 1);
            int n = (bi << 12) + (wi << 6) + hi_;
            keyh[((size_t)h << 16) + n] = ((u64)enc_f(a1) << 32) | (unsigned)(~ai);
            m2h[(h << 16) + n] = a2;
        }
    }
    if (h == 0) {
        __syncthreads();
        if (t == 0) sumx2p[bi * 32 + q] = wred[0] + wred[1] + wred[2] + wred[3];
    }
}

// grid 256: merge halves -> ids + histogram + near-tie flags
__global__ __launch_bounds__(256) void k_merge(
    const u64* __restrict__ keyh, const float* __restrict__ m2h,
    float* __restrict__ out, int* __restrict__ icnt,
    unsigned* __restrict__ rcnt, int* __restrict__ rlist)
{
    int n = blockIdx.x * 256 + threadIdx.x;
    u64 kA = keyh[n], kB = keyh[65536 + n];
    float m2A = m2h[n], m2B = m2h[65536 + n];
    bool wA = kA >= kB;
    u64 kW = wA ? kA : kB, kL = wA ? kB : kA;
    float m2w = wA ? m2A : m2B;
    float sW = dec_f((unsigned)(kW >> 32));
    float sL = dec_f((unsigned)(kL >> 32));
    int code = (int)(~(unsigned)kW);
    out[IDS_OFF + n] = (float)code;
    atomicAdd(&icnt[code], 1);
    float gap = sW - fmaxf(m2w, sL);
    if (gap < TAU) {
        unsigned j = atomicAdd(rcnt, 1u);
        if (j < RCAP) rlist[j] = n;
    }
}

// grid 128: exact fp32 rescore of flagged pixels; writes final ids + icnt fixup
__global__ __launch_bounds__(256) void k_rescue(
    const float* __restrict__ x, const float* __restrict__ embed,
    const float* __restrict__ norms, const unsigned* __restrict__ rcnt,
    const int* __restrict__ rlist, float* __restrict__ out,
    int* __restrict__ icnt)
{
    __shared__ float xs[16][260];
    __shared__ int nn[16];
    __shared__ u64 rk[4][16];
    const int t = threadIdx.x;
    const int l = t & 63;
    const int w = t >> 6;
    int nf = (int)min(*rcnt, (unsigned)RCAP);
    int nch = (nf + 15) >> 4;
    for (int chunk = blockIdx.x; chunk < nch; chunk += gridDim.x) {
        __syncthreads();
        if (t < 16) nn[t] = rlist[(chunk * 16 + t < nf) ? (chunk * 16 + t) : chunk * 16];
        __syncthreads();
        #pragma unroll 4
        for (int p = 0; p < 16; ++p) {
            int n = nn[p];
            int bi = n >> 12, wi = (n >> 6) & 63, hi = n & 63;
            xs[p][t] = x[((size_t)(bi * C_DIM + t)) * 4096 + hi * 64 + wi];
        }
        __syncthreads();
        u64 bk[16];
        #pragma unroll
        for (int p = 0; p < 16; ++p) bk[p] = 0ull;
        for (int rep = 0; rep < 8; ++rep) {
            int d = rep * 256 + t;
            const float* er = embed + (size_t)d * C_DIM;
            float acc[16];
            #pragma unroll
            for (int p = 0; p < 16; ++p) acc[p] = 0.f;
            for (int c = 0; c < C_DIM; c += 4) {
                float4 e4 = *(const float4*)(er + c);
                #pragma unroll
                for (int p = 0; p < 16; ++p) {
                    float4 xv = *(const float4*)&xs[p][c];
                    acc[p] += xv.x * e4.x + xv.y * e4.y + xv.z * e4.z + xv.w * e4.w;
                }
            }
            float nrm = norms[d];
            #pragma unroll
            for (int p = 0; p < 16; ++p) {
                float sc = 2.f * acc[p] - nrm;
                u64 key = ((u64)enc_f(sc) << 32) | (unsigned)(~d);
                if (key > bk[p]) bk[p] = key;
            }
        }
        #pragma unroll
        for (int p = 0; p < 16; ++p) {
            u64 k0 = bk[p];
            #pragma unroll
            for (int o = 32; o; o >>= 1) {
                u64 ok = __shfl_down(k0, o);
                if (ok > k0) k0 = ok;
            }
            if (l == 0) rk[w][p] = k0;
        }
        __syncthreads();
        if (t < 16 && chunk * 16 + t < nf) {
            u64 k0 = rk[0][t];
            if (rk[1][t] > k0) k0 = rk[1][t];
            if (rk[2][t] > k0) k0 = rk[2][t];
            if (rk[3][t] > k0) k0 = rk[3][t];
            int n = nn[t];
            int newid = (int)(~(unsigned)k0);
            int old = (int)out[IDS_OFF + n];
            if (newid != old) {
                out[IDS_OFF + n] = (float)newid;
                atomicAdd(&icnt[old], -1);
                atomicAdd(&icnt[newid], 1);
            }
        }
    }
}

// single block: offsets + sub-block table + cntf + ntot
__global__ __launch_bounds__(256) void k_prefix(const int* __restrict__ icnt,
                                                const float* __restrict__ cs_in,
                                                int* __restrict__ offs,
                                                int* __restrict__ curs,
                                                float* __restrict__ cntf,
                                                int* __restrict__ sbcode,
                                                int* __restrict__ sbstart,
                                                int* __restrict__ sbinfo,
                                                int* __restrict__ nsbtot,
                                                float* __restrict__ ntot) {
    __shared__ int ps[256];
    __shared__ float fs[256];
    const int t = threadIdx.x;
    int c[8], o8[8];
    int s = 0;
    #pragma unroll
    for (int j = 0; j < 8; ++j) c[j] = icnt[t * 8 + j];
    #pragma unroll
    for (int j = 0; j < 8; ++j) { int tmp = c[j]; c[j] = s; s += tmp; }
    ps[t] = s;
    __syncthreads();
    for (int off = 1; off < 256; off <<= 1) {
        int v = (t >= off) ? ps[t - off] : 0;
        __syncthreads();
        ps[t] += v;
        __syncthreads();
    }
    int base = ps[t] - s;
    #pragma unroll
    for (int j = 0; j < 8; ++j) {
        int o = base + c[j];
        o8[j] = o;
        offs[t * 8 + j] = o;
        curs[t * 8 + j] = o;
        cntf[t * 8 + j] = (float)(icnt[t * 8 + j]);
    }
    int s2 = 0;
    int nb[8];
    #pragma unroll
    for (int j = 0; j < 8; ++j) {
        int cnt = icnt[t * 8 + j];
        nb[j] = (cnt + 255) >> 8;
        s2 += nb[j];
    }
    __syncthreads();
    ps[t] = s2;
    __syncthreads();
    for (int off = 1; off < 256; off <<= 1) {
        int v = (t >= off) ? ps[t - off] : 0;
        __syncthreads();
        ps[t] += v;
        __syncthreads();
    }
    int pos = ps[t] - s2;
    #pragma unroll
    for (int j = 0; j < 8; ++j) {
        int code = t * 8 + j;
        int cnt = icnt[code];
        int n = nb[j];
        for (int k = 0; k < n; ++k) {
            sbcode[pos]  = code;
            sbstart[pos] = o8[j] + k * 256;
            int len = cnt - k * 256; if (len > 256) len = 256;
            sbinfo[pos]  = len | ((n > 1) ? (1 << 16) : 0);
            ++pos;
        }
    }
    if (t == 255) *nsbtot = ps[255];
    // ntot = 0.99 * sum(cs_in) + 0.01 * 65536 (assignment-independent)
    float s3 = 0.f;
    #pragma unroll
    for (int j = 0; j < 8; ++j) s3 += cs_in[t * 8 + j];
    fs[t] = s3;
    __syncthreads();
    for (int o = 128; o; o >>= 1) { if (t < o) fs[t] += fs[t + o]; __syncthreads(); }
    if (t == 0) *ntot = MOM * fs[0] + ONE_M * 65536.0f;
}

__global__ __launch_bounds__(256) void k_scatter(const float* __restrict__ out,
                                                 int* __restrict__ curs,
                                                 int* __restrict__ plist) {
    int n = blockIdx.x * 256 + threadIdx.x;
    int id = (int)out[IDS_OFF + n];
    int pos = atomicAdd(&curs[id], 1);
    plist[pos] = n;
}

// grid-stride over sub-blocks: dense esum partials + per-sub-block loss term
__global__ __launch_bounds__(256) void k_esum(
    const float* __restrict__ xt, const float* __restrict__ embed,
    const float* __restrict__ norms, const int* __restrict__ sbcode,
    const int* __restrict__ sbstart, const int* __restrict__ sbinfo,
    const int* __restrict__ plist, const int* __restrict__ nsbtot,
    float* __restrict__ esum, float* __restrict__ lossp)
{
    __shared__ int   ns[256];
    __shared__ float red[256];
    const int t = threadIdx.x;
    const int total = *nsbtot;
    for (int sb = blockIdx.x; sb < total; sb += gridDim.x) {
        const int d     = sbcode[sb];
        const int start = sbstart[sb];
        const int info  = sbinfo[sb];
        const int len   = info & 0xFFFF;
        const bool multi = (info >> 16) != 0;
        __syncthreads();
        if (t < len) ns[t] = plist[start + t];
        __syncthreads();
        float acc = 0.f;
        #pragma unroll 8
        for (int i = 0; i < len; ++i)
            acc += xt[(size_t)ns[i] * C_DIM + t];
        if (multi) atomicAdd(&esum[(size_t)t * D_CODES + d], acc);
        else       esum[(size_t)t * D_CODES + d] = acc;
        red[t] = acc * embed[(size_t)d * C_DIM + t];
        __syncthreads();
        for (int o = 128; o; o >>= 1) {
            if (t < o) red[t] += red[t + o];
            __syncthreads();
        }
        if (t == 0) lossp[sb] = 2.f * red[0] - (float)len * norms[d];
    }
}

// quantized output via LDS-staged embed rows (overwrites the xt region)
__global__ __launch_bounds__(256) void k_quant(
    const float* __restrict__ embed, float* __restrict__ out)
{
    __shared__ int   ids_s[64];
    __shared__ float es[32][257];
    const int t  = threadIdx.x;
    const int bi = blockIdx.x >> 6;
    const int hi = blockIdx.x & 63;
    const int wl = t & 31;
    const int cg = t >> 5;
    if (t < 64) ids_s[t] = (int)out[IDS_OFF + ((size_t)bi << 12) + (t << 6) + hi];
    __syncthreads();
    #pragma unroll
    for (int pass = 0; pass < 2; ++pass) {
        #pragma unroll 8
        for (int p = 0; p < 32; ++p) {
            es[p][t] = embed[(size_t)ids_s[pass * 32 + p] * C_DIM + t];
        }
        __syncthreads();
        #pragma unroll 8
        for (int k = 0; k < 32; ++k) {
            int ch = k * 8 + cg;
            out[Q_OFF + ((size_t)(bi * C_DIM + ch)) * 4096 + hi * 64 + pass * 32 + wl]
                = es[wl][ch];
        }
        __syncthreads();
    }
}

// grid 2049: blocks 0-2047 embed-EMA+new_embed (+NCS via blocks 0-7); block 2048 loss
__global__ __launch_bounds__(256) void k_final(
    const float* __restrict__ cs_in, const float* __restrict__ cntf,
    const float* __restrict__ embed_avg, const float* __restrict__ esum,
    const float* __restrict__ ntotp, const float* __restrict__ lossp,
    const float* __restrict__ sumx2p, float* __restrict__ out)
{
    const int b = blockIdx.x;
    const int t = threadIdx.x;
    if (b < 2048) {
        int ch = b >> 3;
        int d  = ((b & 7) << 8) + t;
        float ntot = *ntotp;
        float ncs  = MOM * cs_in[d] + ONE_M * cntf[d];
        if (b < 8) out[NCS_OFF + d] = ncs;
        float csm  = ntot * (ncs + EPSI) / (ntot + (float)D_CODES * EPSI);
        size_t i = (size_t)ch * D_CODES + d;
        float nea = MOM * embed_avg[i] + ONE_M * esum[i];
        out[NEA_OFF + i] = nea;
        out[NE_OFF + (size_t)d * C_DIM + ch] = nea / csm;
    } else {
        __shared__ float sm[256];
        float s1 = 0.f;
        for (int i = t; i < 512; i += 256) s1 += sumx2p[i];
        float s2 = 0.f;
        for (int i = t; i < SBCAP; i += 256) s2 += lossp[i];
        sm[t] = s1 - s2;
        __syncthreads();
        for (int o = 128; o; o >>= 1) { if (t < o) sm[t] += sm[t + o]; __syncthreads(); }
        if (t == 0) out[LOSS_OFF] = sm[0] / 16777216.f;
    }
}

extern "C" void kernel_launch(void* const* d_in, const int* in_sizes, int n_in,
                              void* d_out, int out_size, void* d_ws, size_t ws_size,
                              hipStream_t stream) {
    const float* x     = (const float*)d_in[0];
    const float* embed = (const float*)d_in[1];
    const float* cs    = (const float*)d_in[2];
    const float* ea    = (const float*)d_in[3];
    float* out = (float*)d_out;
    float* ws  = (float*)d_ws;
    int*      icnt    = (int*)(ws + WS_ICNT);
    float*    cntf    = ws + WS_CNTF;
    int*      offs    = (int*)(ws + WS_OFFS);
    int*      curs    = (int*)(ws + WS_CURS);
    float*    sumx2p  = ws + WS_SUMX2;
    float*    ntot    = ws + WS_NTOT;
    unsigned* rcnt    = (unsigned*)(ws + WS_RCNT);
    int*      nsbtot  = (int*)(ws + WS_NSB);
    float*    norms   = ws + WS_NORMS;
    int*      rlist   = (int*)(ws + WS_RLIST);
    float*    esum    = ws + WS_ESUM;
    float*    e2      = ws + WS_E2;
    u64*      keyh    = (u64*)(ws + WS_KEYH);
    float*    m2h     = ws + WS_M2H;
    int*      plist   = (int*)(ws + WS_PLIST);
    int*      sbcode  = (int*)(ws + WS_SBCODE);
    int*      sbstart = (int*)(ws + WS_SBSTART);
    int*      sbinfo  = (int*)(ws + WS_SBINFO);
    float*    lossp   = ws + WS_LOSSP;
    float*    xt      = out + Q_OFF;   // staged in quantized region, overwritten by k_quant

    k_init<<<2048, 256, 0, stream>>>(embed, e2, norms, esum, icnt, lossp, rcnt);
    k_main<<<1024, 256, 0, stream>>>(x, e2, norms, xt, sumx2p, keyh, m2h);
    k_merge<<<256, 256, 0, stream>>>(keyh, m2h, out, icnt, rcnt, rlist);
    k_rescue<<<128, 256, 0, stream>>>(x, embed, norms, rcnt, rlist, out, icnt);
    k_prefix<<<1, 256, 0, stream>>>(icnt, cs, offs, curs, cntf, sbcode, sbstart,
                                    sbinfo, nsbtot, ntot);
    k_scatter<<<256, 256, 0, stream>>>(out, curs, plist);
    k_esum<<<SBCAP, 256, 0, stream>>>(xt, embed, norms, sbcode, sbstart, sbinfo,
                                      plist, nsbtot, esum, lossp);
    k_quant<<<1024, 256, 0, stream>>>(embed, out);
    k_final<<<2049, 256, 0, stream>>>(cs, cntf, ea, esum, ntot, lossp, sumx2p, out);
}

// Round 8
// 331.266 us; speedup vs baseline: 2.8054x; 1.5583x over previous
//
#include <hip/hip_runtime.h>

#define D_CODES 2048
#define C_DIM   256
#define MOM     0.99f
#define ONE_M   0.01f
#define EPSI    1e-5f
#define TAU     0.10f
#define RCAP    16384
#define SBCAP   2304

// output offsets (floats)
#define Q_OFF    0
#define LOSS_OFF 16777216
#define IDS_OFF  16777217
#define NE_OFF   16842753
#define NCS_OFF  17367041
#define NEA_OFF  17369089

// workspace offsets (floats)
#define WS_ICNT    0
#define WS_CNTF    2048
#define WS_OFFS    4096
#define WS_CURS    6144
#define WS_SUMX2   10240
#define WS_NTOT    11264
#define WS_RCNT    11268
#define WS_NSB     11269
#define WS_NORMS   11272
#define WS_RLIST   13320
#define WS_ESUM    29704
#define WS_E2      553992
#define WS_KEYH    816136
#define WS_M2H     1078280
#define WS_PLIST   1209352
#define WS_SBCODE  1274888
#define WS_SBSTART 1277192
#define WS_SBINFO  1279496
#define WS_LOSSP   1281800

typedef _Float16 half8 __attribute__((ext_vector_type(8)));
typedef __attribute__((ext_vector_type(4))) float f32x4;
typedef unsigned long long u64;

__device__ __forceinline__ f32x4 MFH(half8 a, half8 b, f32x4 c) {
    return __builtin_amdgcn_mfma_f32_16x16x32_f16(a, b, c, 0, 0, 0);
}
__device__ __forceinline__ unsigned enc_f(float v) {
    unsigned u = __float_as_uint(v);
    return (u & 0x80000000u) ? ~u : (u | 0x80000000u);
}
__device__ __forceinline__ float dec_f(unsigned u) {
    return (u & 0x80000000u) ? __uint_as_float(u & 0x7FFFFFFFu)
                             : __uint_as_float(~u);
}

// grid 2048: esum zero everywhere; blocks 0-63 eprep+norms; 64-71 icnt; 72-80 lossp;
// 81 rcnt; 128-383 embed transpose -> etg[c][d] (parked in out's NEA region)
__global__ __launch_bounds__(256) void k_init(
    const float* __restrict__ embed, float* __restrict__ e2f,
    float* __restrict__ norms, float* __restrict__ esum,
    int* __restrict__ icnt, float* __restrict__ lossp,
    unsigned* __restrict__ rcnt, float* __restrict__ etg)
{
    const int b = blockIdx.x, t = threadIdx.x;
    esum[(size_t)b * 256 + t] = 0.f;
    if (b < 64) {
        __shared__ float nrm[32];
        if (t < 32) nrm[t] = 0.f;
        __syncthreads();
        char* e2 = (char*)e2f;
        const int s = b;
        #pragma unroll
        for (int it = 0; it < 4; ++it) {
            int u = it * 256 + t;
            int r = u >> 9, kc = (u >> 6) & 7, l = u & 63;
            int code = s * 32 + r * 16 + (l & 15);
            int ch0  = kc * 32 + ((l >> 4) << 3);
            const float* src = embed + (size_t)code * C_DIM + ch0;
            float4 v0 = *(const float4*)src;
            float4 v1 = *(const float4*)(src + 4);
            float vv[8] = {v0.x, v0.y, v0.z, v0.w, v1.x, v1.y, v1.z, v1.w};
            half8 hh;
            float p = 0.f;
            #pragma unroll
            for (int j = 0; j < 8; ++j) { hh[j] = (_Float16)vv[j]; p += vv[j] * vv[j]; }
            atomicAdd(&nrm[r * 16 + (l & 15)], p);
            char* dst = e2 + (size_t)s * 16384 + (size_t)((r * 8 + kc) * 64 + l) * 16;
            *(half8*)dst = hh;
        }
        __syncthreads();
        if (t < 32) norms[s * 32 + t] = nrm[t];
    } else if (b < 72) {
        icnt[(b - 64) * 256 + t] = 0;
    } else if (b < 81) {
        int j = (b - 72) * 256 + t;
        if (j < SBCAP) lossp[j] = 0.f;
    } else if (b == 81) {
        if (t == 0) *rcnt = 0u;
    } else if (b >= 128 && b < 384) {
        int code0 = (b - 128) * 8;
        #pragma unroll
        for (int j = 0; j < 8; ++j) {
            float v = embed[(size_t)(code0 + j) * C_DIM + t];
            etg[(size_t)t * D_CODES + code0 + j] = v;
        }
    }
}

__device__ __forceinline__ void stage_copy(const char* __restrict__ g, char* lds_base,
                                           int w, int l) {
    #pragma unroll
    for (int i = 0; i < 4; ++i) {
        int off = w * 4096 + i * 1024;
        __builtin_amdgcn_global_load_lds(
            (const __attribute__((address_space(1))) void*)(g + off + l * 16),
            (__attribute__((address_space(3))) void*)(lds_base + off),
            16, 0, 0);
    }
}

// grid 1024: blk = (bi*32+q)*2 + h; half h scans codes [h*1024, h*1024+1024)
// per-pixel top1/top2 written to keyh/m2h[h]; h0 writes sumx2 partials, h1 writes xt
// NOTE launch_bounds (256,2): (256,4) forced a 64-VGPR cap -> fragment spill (r6).
__global__ __launch_bounds__(256, 2) void k_main(
    const float* __restrict__ x, const float* __restrict__ e2f,
    const float* __restrict__ norms, float* __restrict__ xt,
    float* __restrict__ sumx2p, u64* __restrict__ keyh,
    float* __restrict__ m2h)
{
    __shared__ char smem[34816];
    __shared__ float wred[4];
    const int t  = threadIdx.x;
    const int l  = t & 63;
    const int w  = __builtin_amdgcn_readfirstlane(t >> 6);
    const int blk = blockIdx.x;
    const int h  = blk & 1;
    const int q  = (blk >> 1) & 31;
    const int bi = blk >> 6;
    const char* e2 = (const char*)e2f + (size_t)h * 32 * 16384;

    half8 bxh[2][8], bxl[2][8];
    float sx2 = 0.f;
    {
        float* xs = (float*)smem;     // [pl 128][68]
        const int hiq = w >> 1;
        const int wib = (w & 1) * 32;
        for (int c = 0; c < 4; ++c) {
            __syncthreads();
            #pragma unroll
            for (int k = 0; k < 8; ++k) {
                int u = k * 256 + t;
                int wi0 = (u & 15) * 4;
                int hq  = (u >> 4) & 1;
                int chl = u >> 5;
                float4 v = *(const float4*)(x + ((size_t)(bi * C_DIM + c * 64 + chl)) * 4096
                                              + (2 * q + hq) * 64 + wi0);
                if (h == 0) sx2 += v.x * v.x + v.y * v.y + v.z * v.z + v.w * v.w;
                int pb = (hq * 64 + wi0) * 68 + chl;
                xs[pb] = v.x; xs[pb + 68] = v.y; xs[pb + 136] = v.z; xs[pb + 204] = v.w;
            }
            __syncthreads();
            if (h == 1) {       // xt write (transposed, coalesced 256B chunks)
                int plo = t >> 4;
                int cc4 = (t & 15) * 4;
                #pragma unroll
                for (int p8 = 0; p8 < 8; ++p8) {
                    int pl = p8 * 16 + plo;
                    float4 f = *(const float4*)&xs[pl * 68 + cc4];
                    int hq = pl >> 6, wi = pl & 63;
                    size_t n = (size_t)bi * 4096 + (size_t)wi * 64 + (2 * q + hq);
                    *(float4*)(xt + n * C_DIM + c * 64 + cc4) = f;
                }
            }
            // x B-fragments: fp16 hi + fp16 residual
            #pragma unroll
            for (int kcl = 0; kcl < 2; ++kcl) {
                #pragma unroll
                for (int nt = 0; nt < 2; ++nt) {
                    int pl = hiq * 64 + wib + nt * 16 + (l & 15);
                    const float* src = &xs[pl * 68 + kcl * 32 + ((l >> 4) << 3)];
                    float4 f0 = *(const float4*)src;
                    float4 f1 = *(const float4*)(src + 4);
                    float vv[8] = {f0.x, f0.y, f0.z, f0.w, f1.x, f1.y, f1.z, f1.w};
                    half8 hh, rr;
                    #pragma unroll
                    for (int j = 0; j < 8; ++j) {
                        _Float16 hv = (_Float16)vv[j];
                        hh[j] = hv;
                        rr[j] = (_Float16)(vv[j] - (float)hv);
                    }
                    bxh[nt][c * 2 + kcl] = hh;
                    bxl[nt][c * 2 + kcl] = rr;
                }
            }
        }
        __syncthreads();
    }
    if (h == 0) {
        #pragma unroll
        for (int o = 32; o; o >>= 1) sx2 += __shfl_down(sx2, o);
        if (l == 0) wred[w] = sx2;
    }

    float m1[2] = {-3.4e38f, -3.4e38f}, m2[2] = {-3.4e38f, -3.4e38f};
    int   i1[2] = {0, 0};

    stage_copy(e2, smem, w, l);
    __syncthreads();

    for (int s = 0; s < 32; ++s) {
        char* cur = smem + (s & 1) * 16384;
        if (s < 31)
            stage_copy(e2 + (size_t)(s + 1) * 16384, smem + ((s + 1) & 1) * 16384, w, l);

        #pragma unroll
        for (int r = 0; r < 2; ++r) {
            f32x4 z = {0.f, 0.f, 0.f, 0.f};
            f32x4 aA0 = z, aL0 = z, aA1 = z, aL1 = z;
            #pragma unroll
            for (int kc = 0; kc < 8; ++kc) {
                half8 ah = *(const half8*)(cur + ((r * 8 + kc) * 64 + l) * 16);
                aA0 = MFH(ah, bxh[0][kc], aA0);
                aL0 = MFH(ah, bxl[0][kc], aL0);
                aA1 = MFH(ah, bxh[1][kc], aA1);
                aL1 = MFH(ah, bxl[1][kc], aL1);
            }
            int c0 = h * 1024 + s * 32 + r * 16 + ((l >> 4) << 2);
            float4 nrm = *(const float4*)(norms + c0);
            float nr[4] = {nrm.x, nrm.y, nrm.z, nrm.w};
            #pragma unroll
            for (int reg = 0; reg < 4; ++reg) {
                float s0 = 2.f * (aA0[reg] + aL0[reg]) - nr[reg];
                float s1 = 2.f * (aA1[reg] + aL1[reg]) - nr[reg];
                int code = c0 + reg;
                if (s0 > m1[0]) { m2[0] = m1[0]; m1[0] = s0; i1[0] = code; }
                else            { m2[0] = fmaxf(m2[0], s0); }
                if (s1 > m1[1]) { m2[1] = m1[1]; m1[1] = s1; i1[1] = code; }
                else            { m2[1] = fmaxf(m2[1], s1); }
            }
        }
        __syncthreads();
    }

    #pragma unroll
    for (int nt = 0; nt < 2; ++nt) {
        float a1 = m1[nt], a2 = m2[nt];
        int   ai = i1[nt];
        #pragma unroll
        for (int off = 16; off <= 32; off <<= 1) {
            float o1 = __shfl_xor(a1, off);
            int   oi = __shfl_xor(ai, off);
            float o2 = __shfl_xor(a2, off);
            if (o1 > a1)       { a2 = fmaxf(a1, o2); a1 = o1; ai = oi; }
            else if (o1 == a1) { if (oi < ai) ai = oi; a2 = a1; }
            else               { a2 = fmaxf(a2, o1); }
        }
        if (l < 16) {
            int wi = (w & 1) * 32 + nt * 16 + l;
            int hi_ = 2 * q + (w >> 1);
            int n = (bi << 12) + (wi << 6) + hi_;
            keyh[((size_t)h << 16) + n] = ((u64)enc_f(a1) << 32) | (unsigned)(~ai);
            m2h[(h << 16) + n] = a2;
        }
    }
    if (h == 0) {
        __syncthreads();
        if (t == 0) sumx2p[bi * 32 + q] = wred[0] + wred[1] + wred[2] + wred[3];
    }
}

// grid 256: merge halves -> ids + histogram + near-tie flags
__global__ __launch_bounds__(256) void k_merge(
    const u64* __restrict__ keyh, const float* __restrict__ m2h,
    float* __restrict__ out, int* __restrict__ icnt,
    unsigned* __restrict__ rcnt, int* __restrict__ rlist)
{
    int n = blockIdx.x * 256 + threadIdx.x;
    u64 kA = keyh[n], kB = keyh[65536 + n];
    float m2A = m2h[n], m2B = m2h[65536 + n];
    bool wA = kA >= kB;
    u64 kW = wA ? kA : kB, kL = wA ? kB : kA;
    float m2w = wA ? m2A : m2B;
    float sW = dec_f((unsigned)(kW >> 32));
    float sL = dec_f((unsigned)(kL >> 32));
    int code = (int)(~(unsigned)kW);
    out[IDS_OFF + n] = (float)code;
    atomicAdd(&icnt[code], 1);
    float gap = sW - fmaxf(m2w, sL);
    if (gap < TAU) {
        unsigned j = atomicAdd(rcnt, 1u);
        if (j < RCAP) rlist[j] = n;
    }
}

// grid 512: exact fp32 rescore of flagged pixels via xt + transposed embed (etg).
// 8 pixels/chunk; thread t owns codes {rep*1024 + 4t .. +3} -> etg float4 loads
// are perfectly coalesced (the r7 version's per-thread-row reads were a 64-way
// divergent gather -> 258 us latency wall).
__global__ __launch_bounds__(256) void k_rescue(
    const float* __restrict__ xt, const float* __restrict__ etg,
    const float* __restrict__ norms, const unsigned* __restrict__ rcnt,
    const int* __restrict__ rlist, float* __restrict__ out,
    int* __restrict__ icnt)
{
    __shared__ float xs[8][257];
    __shared__ int nn[8];
    __shared__ u64 rk[4][8];
    const int t = threadIdx.x;
    const int l = t & 63;
    const int w = t >> 6;
    int nf = (int)min(*rcnt, (unsigned)RCAP);
    int nch = (nf + 7) >> 3;
    for (int chunk = blockIdx.x; chunk < nch; chunk += gridDim.x) {
        __syncthreads();
        if (t < 8) {
            int idx = chunk * 8 + t;
            nn[t] = rlist[idx < nf ? idx : (nf - 1)];
        }
        __syncthreads();
        #pragma unroll
        for (int p = 0; p < 8; ++p)
            xs[p][t] = xt[(size_t)nn[p] * C_DIM + t];
        __syncthreads();
        u64 bk[8];
        #pragma unroll
        for (int p = 0; p < 8; ++p) bk[p] = 0ull;
        #pragma unroll
        for (int rep = 0; rep < 2; ++rep) {
            const int d0 = rep * 1024 + t * 4;
            f32x4 acc[8];
            #pragma unroll
            for (int p = 0; p < 8; ++p) acc[p] = (f32x4){0.f, 0.f, 0.f, 0.f};
            for (int c = 0; c < C_DIM; ++c) {
                float4 e4 = *(const float4*)(etg + (size_t)c * D_CODES + d0);
                f32x4 ev = {e4.x, e4.y, e4.z, e4.w};
                #pragma unroll
                for (int p = 0; p < 8; ++p)
                    acc[p] += xs[p][c] * ev;
            }
            float4 nr = *(const float4*)(norms + d0);
            float nrr[4] = {nr.x, nr.y, nr.z, nr.w};
            #pragma unroll
            for (int p = 0; p < 8; ++p) {
                #pragma unroll
                for (int j = 0; j < 4; ++j) {
                    float sc = 2.f * acc[p][j] - nrr[j];
                    u64 key = ((u64)enc_f(sc) << 32) | (unsigned)(~(d0 + j));
                    if (key > bk[p]) bk[p] = key;
                }
            }
        }
        #pragma unroll
        for (int p = 0; p < 8; ++p) {
            u64 k0 = bk[p];
            #pragma unroll
            for (int o = 32; o; o >>= 1) {
                u64 ok = __shfl_down(k0, o);
                if (ok > k0) k0 = ok;
            }
            if (l == 0) rk[w][p] = k0;
        }
        __syncthreads();
        if (t < 8 && chunk * 8 + t < nf) {
            u64 k0 = rk[0][t];
            if (rk[1][t] > k0) k0 = rk[1][t];
            if (rk[2][t] > k0) k0 = rk[2][t];
            if (rk[3][t] > k0) k0 = rk[3][t];
            int n = nn[t];
            int newid = (int)(~(unsigned)k0);
            int old = (int)out[IDS_OFF + n];
            if (newid != old) {
                out[IDS_OFF + n] = (float)newid;
                atomicAdd(&icnt[old], -1);
                atomicAdd(&icnt[newid], 1);
            }
        }
    }
}

// single block: offsets + sub-block table + cntf + ntot
__global__ __launch_bounds__(256) void k_prefix(const int* __restrict__ icnt,
                                                const float* __restrict__ cs_in,
                                                int* __restrict__ offs,
                                                int* __restrict__ curs,
                                                float* __restrict__ cntf,
                                                int* __restrict__ sbcode,
                                                int* __restrict__ sbstart,
                                                int* __restrict__ sbinfo,
                                                int* __restrict__ nsbtot,
                                                float* __restrict__ ntot) {
    __shared__ int ps[256];
    __shared__ float fs[256];
    const int t = threadIdx.x;
    int c[8], o8[8];
    int s = 0;
    #pragma unroll
    for (int j = 0; j < 8; ++j) c[j] = icnt[t * 8 + j];
    #pragma unroll
    for (int j = 0; j < 8; ++j) { int tmp = c[j]; c[j] = s; s += tmp; }
    ps[t] = s;
    __syncthreads();
    for (int off = 1; off < 256; off <<= 1) {
        int v = (t >= off) ? ps[t - off] : 0;
        __syncthreads();
        ps[t] += v;
        __syncthreads();
    }
    int base = ps[t] - s;
    #pragma unroll
    for (int j = 0; j < 8; ++j) {
        int o = base + c[j];
        o8[j] = o;
        offs[t * 8 + j] = o;
        curs[t * 8 + j] = o;
        cntf[t * 8 + j] = (float)(icnt[t * 8 + j]);
    }
    int s2 = 0;
    int nb[8];
    #pragma unroll
    for (int j = 0; j < 8; ++j) {
        int cnt = icnt[t * 8 + j];
        nb[j] = (cnt + 255) >> 8;
        s2 += nb[j];
    }
    __syncthreads();
    ps[t] = s2;
    __syncthreads();
    for (int off = 1; off < 256; off <<= 1) {
        int v = (t >= off) ? ps[t - off] : 0;
        __syncthreads();
        ps[t] += v;
        __syncthreads();
    }
    int pos = ps[t] - s2;
    #pragma unroll
    for (int j = 0; j < 8; ++j) {
        int code = t * 8 + j;
        int cnt = icnt[code];
        int n = nb[j];
        for (int k = 0; k < n; ++k) {
            sbcode[pos]  = code;
            sbstart[pos] = o8[j] + k * 256;
            int len = cnt - k * 256; if (len > 256) len = 256;
            sbinfo[pos]  = len | ((n > 1) ? (1 << 16) : 0);
            ++pos;
        }
    }
    if (t == 255) *nsbtot = ps[255];
    // ntot = 0.99 * sum(cs_in) + 0.01 * 65536 (assignment-independent)
    float s3 = 0.f;
    #pragma unroll
    for (int j = 0; j < 8; ++j) s3 += cs_in[t * 8 + j];
    fs[t] = s3;
    __syncthreads();
    for (int o = 128; o; o >>= 1) { if (t < o) fs[t] += fs[t + o]; __syncthreads(); }
    if (t == 0) *ntot = MOM * fs[0] + ONE_M * 65536.0f;
}

__global__ __launch_bounds__(256) void k_scatter(const float* __restrict__ out,
                                                 int* __restrict__ curs,
                                                 int* __restrict__ plist) {
    int n = blockIdx.x * 256 + threadIdx.x;
    int id = (int)out[IDS_OFF + n];
    int pos = atomicAdd(&curs[id], 1);
    plist[pos] = n;
}

// grid-stride over sub-blocks: dense esum partials + per-sub-block loss term
__global__ __launch_bounds__(256) void k_esum(
    const float* __restrict__ xt, const float* __restrict__ embed,
    const float* __restrict__ norms, const int* __restrict__ sbcode,
    const int* __restrict__ sbstart, const int* __restrict__ sbinfo,
    const int* __restrict__ plist, const int* __restrict__ nsbtot,
    float* __restrict__ esum, float* __restrict__ lossp)
{
    __shared__ int   ns[256];
    __shared__ float red[256];
    const int t = threadIdx.x;
    const int total = *nsbtot;
    for (int sb = blockIdx.x; sb < total; sb += gridDim.x) {
        const int d     = sbcode[sb];
        const int start = sbstart[sb];
        const int info  = sbinfo[sb];
        const int len   = info & 0xFFFF;
        const bool multi = (info >> 16) != 0;
        __syncthreads();
        if (t < len) ns[t] = plist[start + t];
        __syncthreads();
        float acc = 0.f;
        #pragma unroll 8
        for (int i = 0; i < len; ++i)
            acc += xt[(size_t)ns[i] * C_DIM + t];
        if (multi) atomicAdd(&esum[(size_t)t * D_CODES + d], acc);
        else       esum[(size_t)t * D_CODES + d] = acc;
        red[t] = acc * embed[(size_t)d * C_DIM + t];
        __syncthreads();
        for (int o = 128; o; o >>= 1) {
            if (t < o) red[t] += red[t + o];
            __syncthreads();
        }
        if (t == 0) lossp[sb] = 2.f * red[0] - (float)len * norms[d];
    }
}

// quantized output via LDS-staged embed rows (overwrites the xt region)
__global__ __launch_bounds__(256) void k_quant(
    const float* __restrict__ embed, float* __restrict__ out)
{
    __shared__ int   ids_s[64];
    __shared__ float es[32][257];
    const int t  = threadIdx.x;
    const int bi = blockIdx.x >> 6;
    const int hi = blockIdx.x & 63;
    const int wl = t & 31;
    const int cg = t >> 5;
    if (t < 64) ids_s[t] = (int)out[IDS_OFF + ((size_t)bi << 12) + (t << 6) + hi];
    __syncthreads();
    #pragma unroll
    for (int pass = 0; pass < 2; ++pass) {
        #pragma unroll 8
        for (int p = 0; p < 32; ++p) {
            es[p][t] = embed[(size_t)ids_s[pass * 32 + p] * C_DIM + t];
        }
        __syncthreads();
        #pragma unroll 8
        for (int k = 0; k < 32; ++k) {
            int ch = k * 8 + cg;
            out[Q_OFF + ((size_t)(bi * C_DIM + ch)) * 4096 + hi * 64 + pass * 32 + wl]
                = es[wl][ch];
        }
        __syncthreads();
    }
}

// grid 2049: blocks 0-2047 embed-EMA+new_embed (+NCS via blocks 0-7); block 2048 loss
__global__ __launch_bounds__(256) void k_final(
    const float* __restrict__ cs_in, const float* __restrict__ cntf,
    const float* __restrict__ embed_avg, const float* __restrict__ esum,
    const float* __restrict__ ntotp, const float* __restrict__ lossp,
    const float* __restrict__ sumx2p, float* __restrict__ out)
{
    const int b = blockIdx.x;
    const int t = threadIdx.x;
    if (b < 2048) {
        int ch = b >> 3;
        int d  = ((b & 7) << 8) + t;
        float ntot = *ntotp;
        float ncs  = MOM * cs_in[d] + ONE_M * cntf[d];
        if (b < 8) out[NCS_OFF + d] = ncs;
        float csm  = ntot * (ncs + EPSI) / (ntot + (float)D_CODES * EPSI);
        size_t i = (size_t)ch * D_CODES + d;
        float nea = MOM * embed_avg[i] + ONE_M * esum[i];
        out[NEA_OFF + i] = nea;
        out[NE_OFF + (size_t)d * C_DIM + ch] = nea / csm;
    } else {
        __shared__ float sm[256];
        float s1 = 0.f;
        for (int i = t; i < 512; i += 256) s1 += sumx2p[i];
        float s2 = 0.f;
        for (int i = t; i < SBCAP; i += 256) s2 += lossp[i];
        sm[t] = s1 - s2;
        __syncthreads();
        for (int o = 128; o; o >>= 1) { if (t < o) sm[t] += sm[t + o]; __syncthreads(); }
        if (t == 0) out[LOSS_OFF] = sm[0] / 16777216.f;
    }
}

extern "C" void kernel_launch(void* const* d_in, const int* in_sizes, int n_in,
                              void* d_out, int out_size, void* d_ws, size_t ws_size,
                              hipStream_t stream) {
    const float* x     = (const float*)d_in[0];
    const float* embed = (const float*)d_in[1];
    const float* cs    = (const float*)d_in[2];
    const float* ea    = (const float*)d_in[3];
    float* out = (float*)d_out;
    float* ws  = (float*)d_ws;
    int*      icnt    = (int*)(ws + WS_ICNT);
    float*    cntf    = ws + WS_CNTF;
    int*      offs    = (int*)(ws + WS_OFFS);
    int*      curs    = (int*)(ws + WS_CURS);
    float*    sumx2p  = ws + WS_SUMX2;
    float*    ntot    = ws + WS_NTOT;
    unsigned* rcnt    = (unsigned*)(ws + WS_RCNT);
    int*      nsbtot  = (int*)(ws + WS_NSB);
    float*    norms   = ws + WS_NORMS;
    int*      rlist   = (int*)(ws + WS_RLIST);
    float*    esum    = ws + WS_ESUM;
    float*    e2      = ws + WS_E2;
    u64*      keyh    = (u64*)(ws + WS_KEYH);
    float*    m2h     = ws + WS_M2H;
    int*      plist   = (int*)(ws + WS_PLIST);
    int*      sbcode  = (int*)(ws + WS_SBCODE);
    int*      sbstart = (int*)(ws + WS_SBSTART);
    int*      sbinfo  = (int*)(ws + WS_SBINFO);
    float*    lossp   = ws + WS_LOSSP;
    float*    xt      = out + Q_OFF;    // staged in quantized region, overwritten by k_quant
    float*    etg     = out + NEA_OFF;  // embed^T scratch, overwritten by k_final

    k_init<<<2048, 256, 0, stream>>>(embed, e2, norms, esum, icnt, lossp, rcnt, etg);
    k_main<<<1024, 256, 0, stream>>>(x, e2, norms, xt, sumx2p, keyh, m2h);
    k_merge<<<256, 256, 0, stream>>>(keyh, m2h, out, icnt, rcnt, rlist);
    k_rescue<<<512, 256, 0, stream>>>(xt, etg, norms, rcnt, rlist, out, icnt);
    k_prefix<<<1, 256, 0, stream>>>(icnt, cs, offs, curs, cntf, sbcode, sbstart,
                                    sbinfo, nsbtot, ntot);
    k_scatter<<<256, 256, 0, stream>>>(out, curs, plist);
    k_esum<<<SBCAP, 256, 0, stream>>>(xt, embed, norms, sbcode, sbstart, sbinfo,
                                      plist, nsbtot, esum, lossp);
    k_quant<<<1024, 256, 0, stream>>>(embed, out);
    k_final<<<2049, 256, 0, stream>>>(cs, cntf, ea, esum, ntot, lossp, sumx2p, out);
}

// Round 9
// 293.182 us; speedup vs baseline: 3.1699x; 1.1299x over previous
//
#include <hip/hip_runtime.h>

#define D_CODES 2048
#define C_DIM   256
#define MOM     0.99f
#define ONE_M   0.01f
#define EPSI    1e-5f
#define TAU     0.16f
#define RCAP    16384
#define SBCAP   2304

// output offsets (floats)
#define Q_OFF    0
#define LOSS_OFF 16777216
#define IDS_OFF  16777217
#define NE_OFF   16842753
#define NCS_OFF  17367041
#define NEA_OFF  17369089

// workspace offsets (floats)
#define WS_ICNT    0
#define WS_CNTF    2048
#define WS_OFFS    4096
#define WS_CURS    6144
#define WS_SUMX2   10240
#define WS_NTOT    11264
#define WS_RCNT    11268
#define WS_NSB     11269
#define WS_NORMS   11272
#define WS_RLIST   13320
#define WS_ESUM    29704
#define WS_E2      553992
#define WS_KEYH    816136
#define WS_M2H     1078280
#define WS_PLIST   1209352
#define WS_SBCODE  1274888
#define WS_SBSTART 1277192
#define WS_SBINFO  1279496
#define WS_LOSSP   1281800

typedef _Float16 half8 __attribute__((ext_vector_type(8)));
typedef __attribute__((ext_vector_type(4))) float f32x4;
typedef unsigned long long u64;

__device__ __forceinline__ f32x4 MFH(half8 a, half8 b, f32x4 c) {
    return __builtin_amdgcn_mfma_f32_16x16x32_f16(a, b, c, 0, 0, 0);
}
__device__ __forceinline__ unsigned enc_f(float v) {
    unsigned u = __float_as_uint(v);
    return (u & 0x80000000u) ? ~u : (u | 0x80000000u);
}
__device__ __forceinline__ float dec_f(unsigned u) {
    return (u & 0x80000000u) ? __uint_as_float(u & 0x7FFFFFFFu)
                             : __uint_as_float(~u);
}

// grid 2048: esum zero everywhere; blocks 0-63 eprep+norms; 64-71 icnt; 72-80 lossp;
// 81 rcnt; 128-383 embed transpose -> etg[c][d] (parked in out's NEA region)
__global__ __launch_bounds__(256) void k_init(
    const float* __restrict__ embed, float* __restrict__ e2f,
    float* __restrict__ norms, float* __restrict__ esum,
    int* __restrict__ icnt, float* __restrict__ lossp,
    unsigned* __restrict__ rcnt, float* __restrict__ etg)
{
    const int b = blockIdx.x, t = threadIdx.x;
    esum[(size_t)b * 256 + t] = 0.f;
    if (b < 64) {
        __shared__ float nrm[32];
        if (t < 32) nrm[t] = 0.f;
        __syncthreads();
        char* e2 = (char*)e2f;
        const int s = b;
        #pragma unroll
        for (int it = 0; it < 4; ++it) {
            int u = it * 256 + t;
            int r = u >> 9, kc = (u >> 6) & 7, l = u & 63;
            int code = s * 32 + r * 16 + (l & 15);
            int ch0  = kc * 32 + ((l >> 4) << 3);
            const float* src = embed + (size_t)code * C_DIM + ch0;
            float4 v0 = *(const float4*)src;
            float4 v1 = *(const float4*)(src + 4);
            float vv[8] = {v0.x, v0.y, v0.z, v0.w, v1.x, v1.y, v1.z, v1.w};
            half8 hh;
            float p = 0.f;
            #pragma unroll
            for (int j = 0; j < 8; ++j) { hh[j] = (_Float16)vv[j]; p += vv[j] * vv[j]; }
            atomicAdd(&nrm[r * 16 + (l & 15)], p);
            char* dst = e2 + (size_t)s * 16384 + (size_t)((r * 8 + kc) * 64 + l) * 16;
            *(half8*)dst = hh;
        }
        __syncthreads();
        if (t < 32) norms[s * 32 + t] = nrm[t];
    } else if (b < 72) {
        icnt[(b - 64) * 256 + t] = 0;
    } else if (b < 81) {
        int j = (b - 72) * 256 + t;
        if (j < SBCAP) lossp[j] = 0.f;
    } else if (b == 81) {
        if (t == 0) *rcnt = 0u;
    } else if (b >= 128 && b < 384) {
        int code0 = (b - 128) * 8;
        #pragma unroll
        for (int j = 0; j < 8; ++j) {
            float v = embed[(size_t)(code0 + j) * C_DIM + t];
            etg[(size_t)t * D_CODES + code0 + j] = v;
        }
    }
}

__device__ __forceinline__ void stage_copy(const char* __restrict__ g, char* lds_base,
                                           int w, int l) {
    #pragma unroll
    for (int i = 0; i < 4; ++i) {
        int off = w * 4096 + i * 1024;
        __builtin_amdgcn_global_load_lds(
            (const __attribute__((address_space(1))) void*)(g + off + l * 16),
            (__attribute__((address_space(3))) void*)(lds_base + off),
            16, 0, 0);
    }
}

// grid 1024: blk = (bi*32+q)*2 + h; half h scans codes [h*1024, h*1024+1024)
// Single fp16 product (no residual): score err sigma ~6e-3, gap sigma ~9e-3;
// TAU=0.16 ~ 17 sigma and all gaps < TAU go to exact rescue.
// xs pad = 65 floats (65 == 1 mod 32): transpose writes & frag reads are 2-way
// bank aliases (free); the old pad=68 made writes a 16-way conflict (16.5M cyc).
// NOTE launch_bounds (256,2): (256,4) forced a VGPR cap -> spill (r6 regression).
__global__ __launch_bounds__(256, 2) void k_main(
    const float* __restrict__ x, const float* __restrict__ e2f,
    const float* __restrict__ norms, float* __restrict__ xt,
    float* __restrict__ sumx2p, u64* __restrict__ keyh,
    float* __restrict__ m2h)
{
    __shared__ char smem[33280];       // prologue xs[128][65] f32; main 2x16KB stages
    __shared__ float wred[4];
    const int t  = threadIdx.x;
    const int l  = t & 63;
    const int w  = __builtin_amdgcn_readfirstlane(t >> 6);
    const int blk = blockIdx.x;
    const int h  = blk & 1;
    const int q  = (blk >> 1) & 31;
    const int bi = blk >> 6;
    const char* e2 = (const char*)e2f + (size_t)h * 32 * 16384;

    half8 bx[2][8];
    float sx2 = 0.f;
    {
        float* xs = (float*)smem;      // [pl 128][65]
        const int hiq = w >> 1;
        const int wib = (w & 1) * 32;
        for (int c = 0; c < 4; ++c) {
            __syncthreads();
            #pragma unroll
            for (int k = 0; k < 8; ++k) {
                int u = k * 256 + t;
                int wi0 = (u & 15) * 4;
                int hq  = (u >> 4) & 1;
                int chl = u >> 5;
                float4 v = *(const float4*)(x + ((size_t)(bi * C_DIM + c * 64 + chl)) * 4096
                                              + (2 * q + hq) * 64 + wi0);
                if (h == 0) sx2 += v.x * v.x + v.y * v.y + v.z * v.z + v.w * v.w;
                int pb = (hq * 64 + wi0) * 65 + chl;
                xs[pb] = v.x; xs[pb + 65] = v.y; xs[pb + 130] = v.z; xs[pb + 195] = v.w;
            }
            __syncthreads();
            if (h == 1) {       // xt write: 4 scalar LDS reads -> float4 global store
                int plo = t >> 4;
                int cc4 = (t & 15) * 4;
                #pragma unroll
                for (int p8 = 0; p8 < 8; ++p8) {
                    int pl = p8 * 16 + plo;
                    const float* sp = &xs[pl * 65 + cc4];
                    float4 f = {sp[0], sp[1], sp[2], sp[3]};
                    int hq = pl >> 6, wi = pl & 63;
                    size_t n = (size_t)bi * 4096 + (size_t)wi * 64 + (2 * q + hq);
                    *(float4*)(xt + n * C_DIM + c * 64 + cc4) = f;
                }
            }
            // x B-fragments: plain fp16 (RTN), scalar LDS reads (2-way banks, free)
            #pragma unroll
            for (int kcl = 0; kcl < 2; ++kcl) {
                #pragma unroll
                for (int nt = 0; nt < 2; ++nt) {
                    int pl = hiq * 64 + wib + nt * 16 + (l & 15);
                    const float* src = &xs[pl * 65 + kcl * 32 + ((l >> 4) << 3)];
                    half8 hh;
                    #pragma unroll
                    for (int j = 0; j < 8; ++j) hh[j] = (_Float16)src[j];
                    bx[nt][c * 2 + kcl] = hh;
                }
            }
        }
        __syncthreads();
    }
    if (h == 0) {
        #pragma unroll
        for (int o = 32; o; o >>= 1) sx2 += __shfl_down(sx2, o);
        if (l == 0) wred[w] = sx2;
    }

    float m1[2] = {-3.4e38f, -3.4e38f}, m2[2] = {-3.4e38f, -3.4e38f};
    int   i1[2] = {0, 0};

    stage_copy(e2, smem, w, l);
    __syncthreads();

    for (int s = 0; s < 32; ++s) {
        char* cur = smem + (s & 1) * 16384;
        if (s < 31)
            stage_copy(e2 + (size_t)(s + 1) * 16384, smem + ((s + 1) & 1) * 16384, w, l);

        #pragma unroll
        for (int r = 0; r < 2; ++r) {
            f32x4 z = {0.f, 0.f, 0.f, 0.f};
            f32x4 aA0 = z, aA1 = z;
            #pragma unroll
            for (int kc = 0; kc < 8; ++kc) {
                half8 ah = *(const half8*)(cur + ((r * 8 + kc) * 64 + l) * 16);
                aA0 = MFH(ah, bx[0][kc], aA0);
                aA1 = MFH(ah, bx[1][kc], aA1);
            }
            int c0 = h * 1024 + s * 32 + r * 16 + ((l >> 4) << 2);
            float4 nrm = *(const float4*)(norms + c0);
            float nr[4] = {nrm.x, nrm.y, nrm.z, nrm.w};
            #pragma unroll
            for (int reg = 0; reg < 4; ++reg) {
                float s0 = 2.f * aA0[reg] - nr[reg];
                float s1 = 2.f * aA1[reg] - nr[reg];
                int code = c0 + reg;
                if (s0 > m1[0]) { m2[0] = m1[0]; m1[0] = s0; i1[0] = code; }
                else            { m2[0] = fmaxf(m2[0], s0); }
                if (s1 > m1[1]) { m2[1] = m1[1]; m1[1] = s1; i1[1] = code; }
                else            { m2[1] = fmaxf(m2[1], s1); }
            }
        }
        __syncthreads();
    }

    #pragma unroll
    for (int nt = 0; nt < 2; ++nt) {
        float a1 = m1[nt], a2 = m2[nt];
        int   ai = i1[nt];
        #pragma unroll
        for (int off = 16; off <= 32; off <<= 1) {
            float o1 = __shfl_xor(a1, off);
            int   oi = __shfl_xor(ai, off);
            float o2 = __shfl_xor(a2, off);
            if (o1 > a1)       { a2 = fmaxf(a1, o2); a1 = o1; ai = oi; }
            else if (o1 == a1) { if (oi < ai) ai = oi; a2 = a1; }
            else               { a2 = fmaxf(a2, o1); }
        }
        if (l < 16) {
            int wi = (w & 1) * 32 + nt * 16 + l;
            int hi_ = 2 * q + (w >> 1);
            int n = (bi << 12) + (wi << 6) + hi_;
            keyh[((size_t)h << 16) + n] = ((u64)enc_f(a1) << 32) | (unsigned)(~ai);
            m2h[(h << 16) + n] = a2;
        }
    }
    if (h == 0) {
        __syncthreads();
        if (t == 0) sumx2p[bi * 32 + q] = wred[0] + wred[1] + wred[2] + wred[3];
    }
}

// grid 256: merge halves -> ids + histogram + near-tie flags
__global__ __launch_bounds__(256) void k_merge(
    const u64* __restrict__ keyh, const float* __restrict__ m2h,
    float* __restrict__ out, int* __restrict__ icnt,
    unsigned* __restrict__ rcnt, int* __restrict__ rlist)
{
    int n = blockIdx.x * 256 + threadIdx.x;
    u64 kA = keyh[n], kB = keyh[65536 + n];
    float m2A = m2h[n], m2B = m2h[65536 + n];
    bool wA = kA >= kB;
    u64 kW = wA ? kA : kB, kL = wA ? kB : kA;
    float m2w = wA ? m2A : m2B;
    float sW = dec_f((unsigned)(kW >> 32));
    float sL = dec_f((unsigned)(kL >> 32));
    int code = (int)(~(unsigned)kW);
    out[IDS_OFF + n] = (float)code;
    atomicAdd(&icnt[code], 1);
    float gap = sW - fmaxf(m2w, sL);
    if (gap < TAU) {
        unsigned j = atomicAdd(rcnt, 1u);
        if (j < RCAP) rlist[j] = n;
    }
}

// grid 512: exact fp32 rescore of flagged pixels via xt + transposed embed (etg).
__global__ __launch_bounds__(256) void k_rescue(
    const float* __restrict__ xt, const float* __restrict__ etg,
    const float* __restrict__ norms, const unsigned* __restrict__ rcnt,
    const int* __restrict__ rlist, float* __restrict__ out,
    int* __restrict__ icnt)
{
    __shared__ float xs[8][257];
    __shared__ int nn[8];
    __shared__ u64 rk[4][8];
    const int t = threadIdx.x;
    const int l = t & 63;
    const int w = t >> 6;
    int nf = (int)min(*rcnt, (unsigned)RCAP);
    int nch = (nf + 7) >> 3;
    for (int chunk = blockIdx.x; chunk < nch; chunk += gridDim.x) {
        __syncthreads();
        if (t < 8) {
            int idx = chunk * 8 + t;
            nn[t] = rlist[idx < nf ? idx : (nf - 1)];
        }
        __syncthreads();
        #pragma unroll
        for (int p = 0; p < 8; ++p)
            xs[p][t] = xt[(size_t)nn[p] * C_DIM + t];
        __syncthreads();
        u64 bk[8];
        #pragma unroll
        for (int p = 0; p < 8; ++p) bk[p] = 0ull;
        #pragma unroll
        for (int rep = 0; rep < 2; ++rep) {
            const int d0 = rep * 1024 + t * 4;
            f32x4 acc[8];
            #pragma unroll
            for (int p = 0; p < 8; ++p) acc[p] = (f32x4){0.f, 0.f, 0.f, 0.f};
            for (int c = 0; c < C_DIM; ++c) {
                float4 e4 = *(const float4*)(etg + (size_t)c * D_CODES + d0);
                f32x4 ev = {e4.x, e4.y, e4.z, e4.w};
                #pragma unroll
                for (int p = 0; p < 8; ++p)
                    acc[p] += xs[p][c] * ev;
            }
            float4 nr = *(const float4*)(norms + d0);
            float nrr[4] = {nr.x, nr.y, nr.z, nr.w};
            #pragma unroll
            for (int p = 0; p < 8; ++p) {
                #pragma unroll
                for (int j = 0; j < 4; ++j) {
                    float sc = 2.f * acc[p][j] - nrr[j];
                    u64 key = ((u64)enc_f(sc) << 32) | (unsigned)(~(d0 + j));
                    if (key > bk[p]) bk[p] = key;
                }
            }
        }
        #pragma unroll
        for (int p = 0; p < 8; ++p) {
            u64 k0 = bk[p];
            #pragma unroll
            for (int o = 32; o; o >>= 1) {
                u64 ok = __shfl_down(k0, o);
                if (ok > k0) k0 = ok;
            }
            if (l == 0) rk[w][p] = k0;
        }
        __syncthreads();
        if (t < 8 && chunk * 8 + t < nf) {
            u64 k0 = rk[0][t];
            if (rk[1][t] > k0) k0 = rk[1][t];
            if (rk[2][t] > k0) k0 = rk[2][t];
            if (rk[3][t] > k0) k0 = rk[3][t];
            int n = nn[t];
            int newid = (int)(~(unsigned)k0);
            int old = (int)out[IDS_OFF + n];
            if (newid != old) {
                out[IDS_OFF + n] = (float)newid;
                atomicAdd(&icnt[old], -1);
                atomicAdd(&icnt[newid], 1);
            }
        }
    }
}

// single block: offsets + sub-block table + cntf + ntot
__global__ __launch_bounds__(256) void k_prefix(const int* __restrict__ icnt,
                                                const float* __restrict__ cs_in,
                                                int* __restrict__ offs,
                                                int* __restrict__ curs,
                                                float* __restrict__ cntf,
                                                int* __restrict__ sbcode,
                                                int* __restrict__ sbstart,
                                                int* __restrict__ sbinfo,
                                                int* __restrict__ nsbtot,
                                                float* __restrict__ ntot) {
    __shared__ int ps[256];
    __shared__ float fs[256];
    const int t = threadIdx.x;
    int c[8], o8[8];
    int s = 0;
    #pragma unroll
    for (int j = 0; j < 8; ++j) c[j] = icnt[t * 8 + j];
    #pragma unroll
    for (int j = 0; j < 8; ++j) { int tmp = c[j]; c[j] = s; s += tmp; }
    ps[t] = s;
    __syncthreads();
    for (int off = 1; off < 256; off <<= 1) {
        int v = (t >= off) ? ps[t - off] : 0;
        __syncthreads();
        ps[t] += v;
        __syncthreads();
    }
    int base = ps[t] - s;
    #pragma unroll
    for (int j = 0; j < 8; ++j) {
        int o = base + c[j];
        o8[j] = o;
        offs[t * 8 + j] = o;
        curs[t * 8 + j] = o;
        cntf[t * 8 + j] = (float)(icnt[t * 8 + j]);
    }
    int s2 = 0;
    int nb[8];
    #pragma unroll
    for (int j = 0; j < 8; ++j) {
        int cnt = icnt[t * 8 + j];
        nb[j] = (cnt + 255) >> 8;
        s2 += nb[j];
    }
    __syncthreads();
    ps[t] = s2;
    __syncthreads();
    for (int off = 1; off < 256; off <<= 1) {
        int v = (t >= off) ? ps[t - off] : 0;
        __syncthreads();
        ps[t] += v;
        __syncthreads();
    }
    int pos = ps[t] - s2;
    #pragma unroll
    for (int j = 0; j < 8; ++j) {
        int code = t * 8 + j;
        int cnt = icnt[code];
        int n = nb[j];
        for (int k = 0; k < n; ++k) {
            sbcode[pos]  = code;
            sbstart[pos] = o8[j] + k * 256;
            int len = cnt - k * 256; if (len > 256) len = 256;
            sbinfo[pos]  = len | ((n > 1) ? (1 << 16) : 0);
            ++pos;
        }
    }
    if (t == 255) *nsbtot = ps[255];
    // ntot = 0.99 * sum(cs_in) + 0.01 * 65536 (assignment-independent)
    float s3 = 0.f;
    #pragma unroll
    for (int j = 0; j < 8; ++j) s3 += cs_in[t * 8 + j];
    fs[t] = s3;
    __syncthreads();
    for (int o = 128; o; o >>= 1) { if (t < o) fs[t] += fs[t + o]; __syncthreads(); }
    if (t == 0) *ntot = MOM * fs[0] + ONE_M * 65536.0f;
}

__global__ __launch_bounds__(256) void k_scatter(const float* __restrict__ out,
                                                 int* __restrict__ curs,
                                                 int* __restrict__ plist) {
    int n = blockIdx.x * 256 + threadIdx.x;
    int id = (int)out[IDS_OFF + n];
    int pos = atomicAdd(&curs[id], 1);
    plist[pos] = n;
}

// grid-stride over sub-blocks: dense esum partials + per-sub-block loss term
__global__ __launch_bounds__(256) void k_esum(
    const float* __restrict__ xt, const float* __restrict__ embed,
    const float* __restrict__ norms, const int* __restrict__ sbcode,
    const int* __restrict__ sbstart, const int* __restrict__ sbinfo,
    const int* __restrict__ plist, const int* __restrict__ nsbtot,
    float* __restrict__ esum, float* __restrict__ lossp)
{
    __shared__ int   ns[256];
    __shared__ float red[256];
    const int t = threadIdx.x;
    const int total = *nsbtot;
    for (int sb = blockIdx.x; sb < total; sb += gridDim.x) {
        const int d     = sbcode[sb];
        const int start = sbstart[sb];
        const int info  = sbinfo[sb];
        const int len   = info & 0xFFFF;
        const bool multi = (info >> 16) != 0;
        __syncthreads();
        if (t < len) ns[t] = plist[start + t];
        __syncthreads();
        float acc = 0.f;
        #pragma unroll 8
        for (int i = 0; i < len; ++i)
            acc += xt[(size_t)ns[i] * C_DIM + t];
        if (multi) atomicAdd(&esum[(size_t)t * D_CODES + d], acc);
        else       esum[(size_t)t * D_CODES + d] = acc;
        red[t] = acc * embed[(size_t)d * C_DIM + t];
        __syncthreads();
        for (int o = 128; o; o >>= 1) {
            if (t < o) red[t] += red[t + o];
            __syncthreads();
        }
        if (t == 0) lossp[sb] = 2.f * red[0] - (float)len * norms[d];
    }
}

// quantized output via LDS-staged embed rows (overwrites the xt region)
__global__ __launch_bounds__(256) void k_quant(
    const float* __restrict__ embed, float* __restrict__ out)
{
    __shared__ int   ids_s[64];
    __shared__ float es[32][257];
    const int t  = threadIdx.x;
    const int bi = blockIdx.x >> 6;
    const int hi = blockIdx.x & 63;
    const int wl = t & 31;
    const int cg = t >> 5;
    if (t < 64) ids_s[t] = (int)out[IDS_OFF + ((size_t)bi << 12) + (t << 6) + hi];
    __syncthreads();
    #pragma unroll
    for (int pass = 0; pass < 2; ++pass) {
        #pragma unroll 8
        for (int p = 0; p < 32; ++p) {
            es[p][t] = embed[(size_t)ids_s[pass * 32 + p] * C_DIM + t];
        }
        __syncthreads();
        #pragma unroll 8
        for (int k = 0; k < 32; ++k) {
            int ch = k * 8 + cg;
            out[Q_OFF + ((size_t)(bi * C_DIM + ch)) * 4096 + hi * 64 + pass * 32 + wl]
                = es[wl][ch];
        }
        __syncthreads();
    }
}

// grid 2049: blocks 0-2047 embed-EMA+new_embed (+NCS via blocks 0-7); block 2048 loss
__global__ __launch_bounds__(256) void k_final(
    const float* __restrict__ cs_in, const float* __restrict__ cntf,
    const float* __restrict__ embed_avg, const float* __restrict__ esum,
    const float* __restrict__ ntotp, const float* __restrict__ lossp,
    const float* __restrict__ sumx2p, float* __restrict__ out)
{
    const int b = blockIdx.x;
    const int t = threadIdx.x;
    if (b < 2048) {
        int ch = b >> 3;
        int d  = ((b & 7) << 8) + t;
        float ntot = *ntotp;
        float ncs  = MOM * cs_in[d] + ONE_M * cntf[d];
        if (b < 8) out[NCS_OFF + d] = ncs;
        float csm  = ntot * (ncs + EPSI) / (ntot + (float)D_CODES * EPSI);
        size_t i = (size_t)ch * D_CODES + d;
        float nea = MOM * embed_avg[i] + ONE_M * esum[i];
        out[NEA_OFF + i] = nea;
        out[NE_OFF + (size_t)d * C_DIM + ch] = nea / csm;
    } else {
        __shared__ float sm[256];
        float s1 = 0.f;
        for (int i = t; i < 512; i += 256) s1 += sumx2p[i];
        float s2 = 0.f;
        for (int i = t; i < SBCAP; i += 256) s2 += lossp[i];
        sm[t] = s1 - s2;
        __syncthreads();
        for (int o = 128; o; o >>= 1) { if (t < o) sm[t] += sm[t + o]; __syncthreads(); }
        if (t == 0) out[LOSS_OFF] = sm[0] / 16777216.f;
    }
}

extern "C" void kernel_launch(void* const* d_in, const int* in_sizes, int n_in,
                              void* d_out, int out_size, void* d_ws, size_t ws_size,
                              hipStream_t stream) {
    const float* x     = (const float*)d_in[0];
    const float* embed = (const float*)d_in[1];
    const float* cs    = (const float*)d_in[2];
    const float* ea    = (const float*)d_in[3];
    float* out = (float*)d_out;
    float* ws  = (float*)d_ws;
    int*      icnt    = (int*)(ws + WS_ICNT);
    float*    cntf    = ws + WS_CNTF;
    int*      offs    = (int*)(ws + WS_OFFS);
    int*      curs    = (int*)(ws + WS_CURS);
    float*    sumx2p  = ws + WS_SUMX2;
    float*    ntot    = ws + WS_NTOT;
    unsigned* rcnt    = (unsigned*)(ws + WS_RCNT);
    int*      nsbtot  = (int*)(ws + WS_NSB);
    float*    norms   = ws + WS_NORMS;
    int*      rlist   = (int*)(ws + WS_RLIST);
    float*    esum    = ws + WS_ESUM;
    float*    e2      = ws + WS_E2;
    u64*      keyh    = (u64*)(ws + WS_KEYH);
    float*    m2h     = ws + WS_M2H;
    int*      plist   = (int*)(ws + WS_PLIST);
    int*      sbcode  = (int*)(ws + WS_SBCODE);
    int*      sbstart = (int*)(ws + WS_SBSTART);
    int*      sbinfo  = (int*)(ws + WS_SBINFO);
    float*    lossp   = ws + WS_LOSSP;
    float*    xt      = out + Q_OFF;    // staged in quantized region, overwritten by k_quant
    float*    etg     = out + NEA_OFF;  // embed^T scratch, overwritten by k_final

    k_init<<<2048, 256, 0, stream>>>(embed, e2, norms, esum, icnt, lossp, rcnt, etg);
    k_main<<<1024, 256, 0, stream>>>(x, e2, norms, xt, sumx2p, keyh, m2h);
    k_merge<<<256, 256, 0, stream>>>(keyh, m2h, out, icnt, rcnt, rlist);
    k_rescue<<<512, 256, 0, stream>>>(xt, etg, norms, rcnt, rlist, out, icnt);
    k_prefix<<<1, 256, 0, stream>>>(icnt, cs, offs, curs, cntf, sbcode, sbstart,
                                    sbinfo, nsbtot, ntot);
    k_scatter<<<256, 256, 0, stream>>>(out, curs, plist);
    k_esum<<<SBCAP, 256, 0, stream>>>(xt, embed, norms, sbcode, sbstart, sbinfo,
                                      plist, nsbtot, esum, lossp);
    k_quant<<<1024, 256, 0, stream>>>(embed, out);
    k_final<<<2049, 256, 0, stream>>>(cs, cntf, ea, esum, ntot, lossp, sumx2p, out);
}